// Round 1
// 368.899 us; speedup vs baseline: 1.2139x; 1.2139x over previous
//
#include <hip/hip_runtime.h>
#include <hip/hip_bf16.h>

#define N_NODES 100000
#define N_EDGES 1600000
#define BN_EPS 1e-5f
#define SCAN_BLOCKS 391   // ceil(100000/256)

typedef __hip_bfloat16 bf16;
typedef unsigned long long ull;
typedef float v2f __attribute__((ext_vector_type(2)));
typedef short bfrag __attribute__((ext_vector_type(8)));   // 8 bf16 = 4 VGPRs
typedef float f32x4 __attribute__((ext_vector_type(4)));

__device__ __forceinline__ float b2f(bf16 v) { return __bfloat162float(v); }
__device__ __forceinline__ float frcp(float x) { return __builtin_amdgcn_rcpf(x); }
__device__ __forceinline__ float fsig(float x) { return frcp(1.0f + __expf(-x)); }
__device__ __forceinline__ float ftanh(float x) {
    return 1.0f - 2.0f * frcp(__expf(2.0f * x) + 1.0f);
}
__device__ __forceinline__ float bfr(uint u) { return __uint_as_float(u << 16); }
__device__ __forceinline__ v2f up(uint u) {
    return (v2f){__uint_as_float(u << 16), __uint_as_float(u & 0xffff0000u)};
}
__device__ __forceinline__ v2f vfma(v2f a, v2f b, v2f c) {
    return __builtin_elementwise_fma(a, b, c);
}
__device__ __forceinline__ uint pk2(const float* p) {
    bf16 a = __float2bfloat16(p[0]), b = __float2bfloat16(p[1]);
    return (uint)*(ushort*)&a | ((uint)*(ushort*)&b << 16);
}
__device__ __forceinline__ uint pkv(v2f v) {
    bf16 a = __float2bfloat16(v.x), b = __float2bfloat16(v.y);
    return (uint)*(ushort*)&a | ((uint)*(ushort*)&b << 16);
}
#define LDS_FENCE() __asm__ volatile("s_waitcnt lgkmcnt(0)" ::: "memory")

// ---- utility ---------------------------------------------------------------
__global__ void k_zero_f(float* __restrict__ p, int n) {
    int i = blockIdx.x * 256 + threadIdx.x;
    if (i < n) p[i] = 0.f;
}
__global__ void k_marker(float* __restrict__ p, int n, float v) {
    int i = blockIdx.x * 256 + threadIdx.x;
    if (i < n) p[i] = v;
}

// ---- packed histogram: pk[d] += (1<<48)|fx(ew); rank = old count -----------
__global__ void k_hist(const int* __restrict__ ei, const float* __restrict__ ew,
                       ull* __restrict__ pk, int* __restrict__ rank) {
    int e = blockIdx.x * 256 + threadIdx.x;
    if (e < N_EDGES) {
        int d = ei[N_EDGES + e];
        ull v = (1ull << 48) | (ull)((double)ew[e] * 4294967296.0);
        ull old = atomicAdd(&pk[d], v);
        rank[e] = (int)(old >> 48);
    }
}

// ---- scan stage 1: per-block sums of counts --------------------------------
__global__ void k_bsum(const ull* __restrict__ pk, int* __restrict__ bsum) {
    __shared__ int s[256];
    int idx = blockIdx.x * 256 + threadIdx.x;
    s[threadIdx.x] = (idx < N_NODES) ? (int)(pk[idx] >> 48) : 0;
    __syncthreads();
    for (int st = 128; st >= 1; st >>= 1) {
        if (threadIdx.x < st) s[threadIdx.x] += s[threadIdx.x + st];
        __syncthreads();
    }
    if (threadIdx.x == 0) bsum[blockIdx.x] = s[0];
}

// ---- scan stage 2 (fused): block base via reduction + local scan -> off ----
__global__ void k_scan3(const ull* __restrict__ pk, const int* __restrict__ bsum,
                        int* __restrict__ off, float* __restrict__ deg) {
    __shared__ int red[256];
    __shared__ int wsum[4];
    int tid = threadIdx.x;
    int acc = 0;
    for (int i = tid; i < SCAN_BLOCKS; i += 256)
        if (i < blockIdx.x) acc += bsum[i];
    red[tid] = acc; __syncthreads();
    for (int st = 128; st >= 1; st >>= 1) {
        if (tid < st) red[tid] += red[tid + st];
        __syncthreads();
    }
    int bbase = red[0];
    int idx = blockIdx.x * 256 + tid;
    int lane = tid & 63, w = tid >> 6;
    ull pv = (idx < N_NODES) ? pk[idx] : 0ull;
    int c = (int)(pv >> 48);
    int s = c;
    for (int d = 1; d < 64; d <<= 1) {
        int u = __shfl_up(s, d, 64);
        if (lane >= d) s += u;
    }
    if (lane == 63) wsum[w] = s;
    __syncthreads();
    int wb = 0;
    for (int i = 0; i < w; i++) wb += wsum[i];
    int e = bbase + wb + s - c;                  // exclusive
    if (idx < N_NODES) {
        off[idx] = e;
        deg[idx] = (float)((double)(pv & 0xFFFFFFFFFFFFull) * (1.0 / 4294967296.0));
    }
    if (idx == 0) off[N_NODES] = N_EDGES;        // all dst are in-range
}

// ---- scatter edges into CSR slots as {src, norm} — NO atomics --------------
__global__ void k_scatter(const int* __restrict__ ei, const float* __restrict__ ew,
                          const float* __restrict__ deg, const int* __restrict__ off,
                          const int* __restrict__ rank, int2* __restrict__ epk) {
    int e = blockIdx.x * 256 + threadIdx.x;
    if (e < N_EDGES) {
        int s = ei[e], d = ei[N_EDGES + e];
        float nm = ew[e] * rsqrtf((deg[s] + 1.0f) * (deg[d] + 1.0f));
        epk[off[d] + rank[e]] = make_int2(s, __float_as_int(nm));
    }
}

// ---- column sums of x (for skip_avg) ---------------------------------------
__global__ void k_xmean(const float* __restrict__ x, float* __restrict__ xsum) {
    __shared__ float s[256];
    int f = threadIdx.x & 31, rg = threadIdx.x >> 5;
    float acc = 0.f;
    for (int n = blockIdx.x * 8 + rg; n < N_NODES; n += gridDim.x * 8)
        acc += x[n * 32 + f];
    s[threadIdx.x] = acc; __syncthreads();
    for (int st = 128; st >= 32; st >>= 1) {
        if (threadIdx.x < st) s[threadIdx.x] += s[threadIdx.x + st];
        __syncthreads();
    }
    if (threadIdx.x < 32) atomicAdd(&xsum[threadIdx.x], s[threadIdx.x]);
}

// ---- A = x @ W1 (fp32 in, bf16 out) ----------------------------------------
__global__ void k_xw1(const float* __restrict__ x, const float* __restrict__ w,
                      bf16* __restrict__ A) {
    __shared__ float Ws[32 * 33];
    __shared__ float xs[256];
    for (int i = threadIdx.x; i < 1024; i += 256)
        Ws[(i >> 5) * 33 + (i & 31)] = w[i];
    long base = (long)blockIdx.x * 256;
    xs[threadIdx.x] = x[base + threadIdx.x];
    __syncthreads();
    int r = threadIdx.x >> 5, h = threadIdx.x & 31;
    float acc = 0.f;
#pragma unroll
    for (int f = 0; f < 32; f++) acc += xs[r * 32 + f] * Ws[f * 33 + h];
    A[base + threadIdx.x] = __float2bfloat16(acc);
}

// ---- pull-mode GCN: 4 lanes/node, uint4 (8-feature) gathers ----------------
// Each quad lane owns feature slice [8*fp, 8*fp+8). A 64-lane wave covers 16
// nodes; each of the 4 batched gather instructions has 16 distinct 64B lines
// in flight (64 lines/wave) vs 4 lines/instr in the 16-lane version ->
// 4x memory-level parallelism for the latency-bound random gather of A.
// Tail edges folded into the batch via clamped index + zeroed norm.
__global__ __launch_bounds__(256) void k_gcn(
    const int* __restrict__ off, const int2* __restrict__ epk,
    const bf16* __restrict__ A, const float* __restrict__ deg,
    const float* __restrict__ bias, bf16* __restrict__ B,
    float* __restrict__ sum, float* __restrict__ sq) {
    __shared__ float rS[4][4][8];
    __shared__ float rQ[4][4][8];
    const uint4* A4 = (const uint4*)A;
    uint4* B4 = (uint4*)B;
    int tid = threadIdx.x, fp = tid & 3, q = tid >> 2;
    int n = blockIdx.x * 64 + q;
    bool valid = n < N_NODES;

    v2f bv0 = (v2f){bias[8 * fp + 0], bias[8 * fp + 1]};
    v2f bv1 = (v2f){bias[8 * fp + 2], bias[8 * fp + 3]};
    v2f bv2 = (v2f){bias[8 * fp + 4], bias[8 * fp + 5]};
    v2f bv3 = (v2f){bias[8 * fp + 6], bias[8 * fp + 7]};

    v2f aA0 = (v2f)0.f, aA1 = (v2f)0.f, aA2 = (v2f)0.f, aA3 = (v2f)0.f;
    v2f aB0 = (v2f)0.f, aB1 = (v2f)0.f, aB2 = (v2f)0.f, aB3 = (v2f)0.f;

    int lo = 0, hi = 0;
    if (valid) { lo = off[n]; hi = off[n + 1]; }

    for (int p = lo; p < hi; p += 4) {
        int p1 = min(p + 1, hi - 1), p2 = min(p + 2, hi - 1), p3 = min(p + 3, hi - 1);
        int2 e0 = epk[p], e1 = epk[p1], e2 = epk[p2], e3 = epk[p3];
        float n0 = __int_as_float(e0.y);
        float n1 = (p + 1 < hi) ? __int_as_float(e1.y) : 0.f;
        float n2 = (p + 2 < hi) ? __int_as_float(e2.y) : 0.f;
        float n3 = (p + 3 < hi) ? __int_as_float(e3.y) : 0.f;
        uint4 g0 = A4[(long)e0.x * 4 + fp];
        uint4 g1 = A4[(long)e1.x * 4 + fp];
        uint4 g2 = A4[(long)e2.x * 4 + fp];
        uint4 g3 = A4[(long)e3.x * 4 + fp];
        v2f v0 = (v2f){n0, n0}, v1 = (v2f){n1, n1};
        v2f v2 = (v2f){n2, n2}, v3 = (v2f){n3, n3};
        aA0 = vfma(up(g0.x), v0, aA0); aA1 = vfma(up(g0.y), v0, aA1);
        aA2 = vfma(up(g0.z), v0, aA2); aA3 = vfma(up(g0.w), v0, aA3);
        aA0 = vfma(up(g1.x), v1, aA0); aA1 = vfma(up(g1.y), v1, aA1);
        aA2 = vfma(up(g1.z), v1, aA2); aA3 = vfma(up(g1.w), v1, aA3);
        aB0 = vfma(up(g2.x), v2, aB0); aB1 = vfma(up(g2.y), v2, aB1);
        aB2 = vfma(up(g2.z), v2, aB2); aB3 = vfma(up(g2.w), v2, aB3);
        aB0 = vfma(up(g3.x), v3, aB0); aB1 = vfma(up(g3.y), v3, aB1);
        aB2 = vfma(up(g3.z), v3, aB2); aB3 = vfma(up(g3.w), v3, aB3);
    }

    v2f bns0 = (v2f)0.f, bns1 = (v2f)0.f, bns2 = (v2f)0.f, bns3 = (v2f)0.f;
    v2f bnq0 = (v2f)0.f, bnq1 = (v2f)0.f, bnq2 = (v2f)0.f, bnq3 = (v2f)0.f;

    if (valid) {
        float si = frcp(deg[n] + 1.0f);
        v2f sv = (v2f){si, si};
        uint4 qs = A4[(long)n * 4 + fp];
        v2f o0 = vfma(up(qs.x), sv, aA0 + aB0) + bv0;
        v2f o1 = vfma(up(qs.y), sv, aA1 + aB1) + bv1;
        v2f o2 = vfma(up(qs.z), sv, aA2 + aB2) + bv2;
        v2f o3 = vfma(up(qs.w), sv, aA3 + aB3) + bv3;
        o0.x = fmaxf(o0.x, 0.f); o0.y = fmaxf(o0.y, 0.f);
        o1.x = fmaxf(o1.x, 0.f); o1.y = fmaxf(o1.y, 0.f);
        o2.x = fmaxf(o2.x, 0.f); o2.y = fmaxf(o2.y, 0.f);
        o3.x = fmaxf(o3.x, 0.f); o3.y = fmaxf(o3.y, 0.f);
        uint4 ov = make_uint4(pkv(o0), pkv(o1), pkv(o2), pkv(o3));
        B4[(long)n * 4 + fp] = ov;
        bns0 = o0; bns1 = o1; bns2 = o2; bns3 = o3;
        bnq0 = o0 * o0; bnq1 = o1 * o1; bnq2 = o2 * o2; bnq3 = o3 * o3;
    }

    // wave-level reduce across quads (lanes with same fp share a feat slice)
#pragma unroll
    for (int st = 4; st <= 32; st <<= 1) {
        bns0.x += __shfl_xor(bns0.x, st); bns0.y += __shfl_xor(bns0.y, st);
        bns1.x += __shfl_xor(bns1.x, st); bns1.y += __shfl_xor(bns1.y, st);
        bns2.x += __shfl_xor(bns2.x, st); bns2.y += __shfl_xor(bns2.y, st);
        bns3.x += __shfl_xor(bns3.x, st); bns3.y += __shfl_xor(bns3.y, st);
        bnq0.x += __shfl_xor(bnq0.x, st); bnq0.y += __shfl_xor(bnq0.y, st);
        bnq1.x += __shfl_xor(bnq1.x, st); bnq1.y += __shfl_xor(bnq1.y, st);
        bnq2.x += __shfl_xor(bnq2.x, st); bnq2.y += __shfl_xor(bnq2.y, st);
        bnq3.x += __shfl_xor(bnq3.x, st); bnq3.y += __shfl_xor(bnq3.y, st);
    }
    int lane = tid & 63, wv = tid >> 6;
    if (lane < 4) {
        rS[wv][lane][0] = bns0.x; rS[wv][lane][1] = bns0.y;
        rS[wv][lane][2] = bns1.x; rS[wv][lane][3] = bns1.y;
        rS[wv][lane][4] = bns2.x; rS[wv][lane][5] = bns2.y;
        rS[wv][lane][6] = bns3.x; rS[wv][lane][7] = bns3.y;
        rQ[wv][lane][0] = bnq0.x; rQ[wv][lane][1] = bnq0.y;
        rQ[wv][lane][2] = bnq1.x; rQ[wv][lane][3] = bnq1.y;
        rQ[wv][lane][4] = bnq2.x; rQ[wv][lane][5] = bnq2.y;
        rQ[wv][lane][6] = bnq3.x; rQ[wv][lane][7] = bnq3.y;
    }
    __syncthreads();
    if (tid < 32) {
        float ts = 0.f, tq = 0.f;
#pragma unroll
        for (int w = 0; w < 4; w++) {
            ts += rS[w][tid >> 3][tid & 7];
            tq += rQ[w][tid >> 3][tid & 7];
        }
        atomicAdd(&sum[tid], ts);
        atomicAdd(&sq[tid], tq);
    }
}

// ---- H = affine(B) (bf16); A = H @ W2 (bf16); BN1 finalize fused -----------
__global__ void k_aff_xw(const bf16* __restrict__ B, const float* __restrict__ sum,
                         const float* __restrict__ sq, const float* __restrict__ g,
                         const float* __restrict__ be, const float* __restrict__ w,
                         bf16* __restrict__ H, bf16* __restrict__ A) {
    __shared__ float Ws[32 * 33];
    __shared__ float hs[256];
    __shared__ float sc[32], sh[32];
    int tid = threadIdx.x;
    if (tid < 32) {
        float mu = sum[tid] / (float)N_NODES;
        float var = sq[tid] / (float)N_NODES - mu * mu;
        float rs = rsqrtf(var + BN_EPS) * g[tid];
        sc[tid] = rs;
        sh[tid] = be[tid] - mu * rs;
    }
    for (int i = tid; i < 1024; i += 256)
        Ws[(i >> 5) * 33 + (i & 31)] = w[i];
    __syncthreads();
    long base = (long)blockIdx.x * 256;
    int f = tid & 31;
    float h = b2f(B[base + tid]) * sc[f] + sh[f];
    H[base + tid] = __float2bfloat16(h);
    hs[tid] = h;
    __syncthreads();
    int r = tid >> 5, hc = tid & 31;
    float acc = 0.f;
#pragma unroll
    for (int k = 0; k < 32; k++) acc += hs[r * 32 + k] * Ws[k * 33 + hc];
    A[base + tid] = __float2bfloat16(acc);
}

// ---- per-node dense stack via MFMA; BN2/fc1-const/bias finalize fused ------
// 128 nodes/block, 4 waves, each wave owns 2 disjoint 16-node M-tiles.
// Layouts (verified): A[m=lane&15][k=quad*8+j], B[k=quad*8+j][n=lane&15],
// C/D[row=quad*4+r][col=lane&15].
#define CATP 72
#define WP1  72
#define WP2  40
#define FP1  72
#define HP   40
__global__ __launch_bounds__(256) void k_final(
    const bf16* __restrict__ Hb, const bf16* __restrict__ Bb,
    const float* __restrict__ bn2sum, const float* __restrict__ bn2sq,
    const float* __restrict__ g2, const float* __restrict__ be2,
    const float* __restrict__ xsum,
    const float* __restrict__ wih1, const float* __restrict__ wih2,
    const float* __restrict__ fw1, const float* __restrict__ fw2,
    const float* __restrict__ fb2, const float* __restrict__ fb1,
    const float* __restrict__ bih1, const float* __restrict__ bhh1,
    const float* __restrict__ bih2, const float* __restrict__ bhh2,
    float* __restrict__ out) {
    __shared__ ushort cat[128 * CATP];
    __shared__ ushort W1s[96 * WP1];
    __shared__ ushort W2s[96 * WP2];
    __shared__ ushort F1s[32 * FP1];
    __shared__ ushort h1s[128 * HP];
    __shared__ ushort h2s[128 * HP];
    __shared__ float lb1s[128], lb2s[128], fc1s[32], fw2s[32], sc2[32], sh2[32];
    int tid = threadIdx.x;
    if (tid < 128) { lb1s[tid] = bih1[tid] + bhh1[tid]; lb2s[tid] = bih2[tid] + bhh2[tid]; }
    if (tid >= 128 && tid < 160) {
        int t = tid - 128;
        float mu = bn2sum[t] / (float)N_NODES;
        float var = bn2sq[t] / (float)N_NODES - mu * mu;
        float rs = rsqrtf(var + BN_EPS) * g2[t];
        sc2[t] = rs;
        sh2[t] = be2[t] - mu * rs;
        fw2s[t] = fw2[t];
        float c = fb1[t];
        for (int f = 0; f < 32; f++)
            c += (xsum[f] / (float)N_NODES) * fw1[t * 96 + 64 + f];
        fc1s[t] = c;
    }
    // W1s rows = gate-cols n: 0..31 -> wih1 row n (i), 32..63 -> 64+(n-32) (g),
    // 64..95 -> 96+(n-64) (o). Same mapping for W2s/wih2.
    for (int i = tid; i < 96 * 8; i += 256) {
        int row = i >> 3, q = i & 7;
        int c = row & 31, t = row >> 5;
        int srow = (t == 0) ? c : ((t == 1) ? 64 + c : 96 + c);
        const float* b = wih1 + srow * 64 + q * 8;
        *(uint4*)&W1s[row * WP1 + q * 8] =
            make_uint4(pk2(b), pk2(b + 2), pk2(b + 4), pk2(b + 6));
    }
    for (int i = tid; i < 96 * 4; i += 256) {
        int row = i >> 2, q = i & 3;
        int c = row & 31, t = row >> 5;
        int srow = (t == 0) ? c : ((t == 1) ? 64 + c : 96 + c);
        const float* b = wih2 + srow * 32 + q * 8;
        *(uint4*)&W2s[row * WP2 + q * 8] =
            make_uint4(pk2(b), pk2(b + 2), pk2(b + 4), pk2(b + 6));
    }
    for (int i = tid; i < 32 * 8; i += 256) {
        int row = i >> 3, q = i & 7;
        const float* b = fw1 + row * 96 + q * 8;
        *(uint4*)&F1s[row * FP1 + q * 8] =
            make_uint4(pk2(b), pk2(b + 2), pk2(b + 4), pk2(b + 6));
    }
    __syncthreads();
    // ---- stage cat[node][0..63] = [H | affine(B)] --------------------------
    {
        int ni = tid >> 1, hf = tid & 1;
        int node = blockIdx.x * 128 + ni;
        int nc = node < N_NODES ? node : N_NODES - 1;
        const uint4* src = (const uint4*)((const ushort*)(hf ? Bb : Hb) + (long)nc * 32);
        ushort* dst = &cat[ni * CATP + hf * 32];
        if (hf == 0) {
#pragma unroll
            for (int q = 0; q < 4; q++) *(uint4*)(dst + q * 8) = src[q];
        } else {
#pragma unroll
            for (int q = 0; q < 4; q++) {
                uint4 v = src[q];
                uint w[4] = {v.x, v.y, v.z, v.w};
                uint o[4];
#pragma unroll
                for (int r = 0; r < 4; r++) {
                    int e = q * 8 + r * 2;
                    o[r] = pkv(vfma(up(w[r]), (v2f){sc2[e], sc2[e + 1]},
                                    (v2f){sh2[e], sh2[e + 1]}));
                }
                *(uint4*)(dst + q * 8) = make_uint4(o[0], o[1], o[2], o[3]);
            }
        }
    }
    __syncthreads();
    // ---- compute: wave wv owns M-tiles wv*2, wv*2+1 ------------------------
    int l = tid & 63, wv = tid >> 6;
    int quad = l >> 4, mr = l & 15;
    float fb2v = fb2[0];
#pragma unroll
    for (int it = 0; it < 2; it++) {
        int mt = wv * 2 + it;
        int mb = mt * 16;
        // LSTM1 gates
        bfrag a0 = *(const bfrag*)&cat[(mb + mr) * CATP + quad * 8];
        bfrag a1 = *(const bfrag*)&cat[(mb + mr) * CATP + 32 + quad * 8];
        f32x4 g[6];
#pragma unroll
        for (int nt = 0; nt < 6; nt++) {
            bfrag b0 = *(const bfrag*)&W1s[(nt * 16 + mr) * WP1 + quad * 8];
            bfrag b1 = *(const bfrag*)&W1s[(nt * 16 + mr) * WP1 + 32 + quad * 8];
            f32x4 z = {0.f, 0.f, 0.f, 0.f};
            z = __builtin_amdgcn_mfma_f32_16x16x32_bf16(a0, b0, z, 0, 0, 0);
            z = __builtin_amdgcn_mfma_f32_16x16x32_bf16(a1, b1, z, 0, 0, 0);
            g[nt] = z;
        }
#pragma unroll
        for (int t = 0; t < 2; t++) {
            int c = t * 16 + mr;
            float bi = lb1s[c], bg = lb1s[64 + c], bo = lb1s[96 + c];
#pragma unroll
            for (int r = 0; r < 4; r++) {
                float c1 = fsig(g[t][r] + bi) * ftanh(g[2 + t][r] + bg);
                float h = fsig(g[4 + t][r] + bo) * ftanh(c1);
                bf16 hb = __float2bfloat16(h);
                h1s[(mb + quad * 4 + r) * HP + c] = *(ushort*)&hb;
            }
        }
        LDS_FENCE();
        // LSTM2 gates
        bfrag ha = *(const bfrag*)&h1s[(mb + mr) * HP + quad * 8];
        f32x4 g2r[6];
#pragma unroll
        for (int nt = 0; nt < 6; nt++) {
            bfrag b = *(const bfrag*)&W2s[(nt * 16 + mr) * WP2 + quad * 8];
            f32x4 z = {0.f, 0.f, 0.f, 0.f};
            z = __builtin_amdgcn_mfma_f32_16x16x32_bf16(ha, b, z, 0, 0, 0);
            g2r[nt] = z;
        }
#pragma unroll
        for (int t = 0; t < 2; t++) {
            int c = t * 16 + mr;
            float bi = lb2s[c], bg = lb2s[64 + c], bo = lb2s[96 + c];
#pragma unroll
            for (int r = 0; r < 4; r++) {
                float c2 = fsig(g2r[t][r] + bi) * ftanh(g2r[2 + t][r] + bg);
                float h = fsig(g2r[4 + t][r] + bo) * ftanh(c2);
                bf16 hb = __float2bfloat16(h);
                h2s[(mb + quad * 4 + r) * HP + c] = *(ushort*)&hb;
            }
        }
        LDS_FENCE();
        // fc1 (K=32 from hn1 via F1 cols 0..31, K=32 from hn2 via cols 32..63)
        bfrag hb2 = *(const bfrag*)&h2s[(mb + mr) * HP + quad * 8];
        f32x4 zt[2];
#pragma unroll
        for (int nt = 0; nt < 2; nt++) {
            bfrag f0 = *(const bfrag*)&F1s[(nt * 16 + mr) * FP1 + quad * 8];
            bfrag f1 = *(const bfrag*)&F1s[(nt * 16 + mr) * FP1 + 32 + quad * 8];
            f32x4 z = {0.f, 0.f, 0.f, 0.f};
            z = __builtin_amdgcn_mfma_f32_16x16x32_bf16(ha, f0, z, 0, 0, 0);
            z = __builtin_amdgcn_mfma_f32_16x16x32_bf16(hb2, f1, z, 0, 0, 0);
            zt[nt] = z;
        }
        // epilogue: relu(z + fc1c) . fw2, reduce over 32 cols
#pragma unroll
        for (int r = 0; r < 4; r++) {
            float s = 0.f;
#pragma unroll
            for (int t = 0; t < 2; t++) {
                int j = t * 16 + mr;
                s += fmaxf(zt[t][r] + fc1s[j], 0.f) * fw2s[j];
            }
            s += __shfl_xor(s, 1); s += __shfl_xor(s, 2);
            s += __shfl_xor(s, 4); s += __shfl_xor(s, 8);
            int node = blockIdx.x * 128 + mb + quad * 4 + r;
            if (mr == 0 && node < N_NODES) out[node] = s + fb2v;
        }
    }
}

extern "C" void kernel_launch(void* const* d_in, const int* in_sizes, int n_in,
                              void* d_out, int out_size, void* d_ws, size_t ws_size,
                              hipStream_t stream) {
    const float* x    = (const float*)d_in[0];
    const int*   ei   = (const int*)d_in[1];
    const float* ew   = (const float*)d_in[2];
    const float* w1   = (const float*)d_in[3];
    const float* b1   = (const float*)d_in[4];
    const float* g1   = (const float*)d_in[5];
    const float* be1  = (const float*)d_in[6];
    const float* w2   = (const float*)d_in[7];
    const float* b2   = (const float*)d_in[8];
    const float* g2   = (const float*)d_in[9];
    const float* be2  = (const float*)d_in[10];
    const float* wih1 = (const float*)d_in[11];
    const float* bih1 = (const float*)d_in[13];
    const float* bhh1 = (const float*)d_in[14];
    const float* wih2 = (const float*)d_in[15];
    const float* bih2 = (const float*)d_in[17];
    const float* bhh2 = (const float*)d_in[18];
    const float* fw1  = (const float*)d_in[19];
    const float* fb1  = (const float*)d_in[20];
    const float* fw2  = (const float*)d_in[21];
    const float* fb2  = (const float*)d_in[22];
    float* out = (float*)d_out;

    // ---- workspace layout (40.5 MB; proven ws >= 41.1 MB from r3/r4) -------
    char* ws = (char*)d_ws;
    float* stats = (float*)ws;                          // 160 floats used
    float* xsum   = stats + 0;
    float* bn1sum = stats + 32;
    float* bn1sq  = stats + 64;
    float* bn2sum = stats + 96;
    float* bn2sq  = stats + 128;
    ull*   pk    = (ull*)  (ws + 4096);                 // 100000 ull -> 804,096
    int*   bsum  = (int*)  (ws + 804096);               // 391 i
    int*   off   = (int*)  (ws + 1048576);              // 100001 i -> 1,448,580
    float* deg   = (float*)(ws + 1572864);              // 100000 f -> 1,972,864
    int2*  epk   = (int2*) (ws + 2097152);              // 1.6M int2 -> 14,897,152
    int*   rank  = (int*)  (ws + 14897152);             // 1.6M i -> 21,297,152
    bf16*  A     = (bf16*) (ws + 21297152);             // 6.4MB -> 27,697,152
    bf16*  H     = (bf16*) (ws + 27697152);             // 6.4MB -> 34,097,152
    bf16*  B     = (bf16*) (ws + 34097152);             // 6.4MB -> 40,497,152

    if (ws_size < 40497152ull) {
        k_marker<<<(N_NODES + 255) / 256, 256, 0, stream>>>(out, N_NODES, 911.f);
        return;
    }

    // zero stats + pk in one shot (bytes 0 .. 804,096)
    k_zero_f<<<786, 256, 0, stream>>>(stats, 201024);

    k_hist<<<6250, 256, 0, stream>>>(ei, ew, pk, rank);
    k_bsum<<<SCAN_BLOCKS, 256, 0, stream>>>(pk, bsum);
    k_scan3<<<SCAN_BLOCKS, 256, 0, stream>>>(pk, bsum, off, deg);
    k_scatter<<<6250, 256, 0, stream>>>(ei, ew, deg, off, rank, epk);
    k_xmean<<<400, 256, 0, stream>>>(x, xsum);
    k_xw1<<<12500, 256, 0, stream>>>(x, w1, A);
    k_gcn<<<1563, 256, 0, stream>>>(off, epk, A, deg, b1, B, bn1sum, bn1sq);
    k_aff_xw<<<12500, 256, 0, stream>>>(B, bn1sum, bn1sq, g1, be1, w2, H, A);
    k_gcn<<<1563, 256, 0, stream>>>(off, epk, A, deg, b2, B, bn2sum, bn2sq);
    k_final<<<782, 256, 0, stream>>>(H, B, bn2sum, bn2sq, g2, be2, xsum,
                                     wih1, wih2, fw1, fw2, fb2, fb1,
                                     bih1, bhh1, bih2, bhh2, out);
}

// Round 2
// 359.901 us; speedup vs baseline: 1.2443x; 1.0250x over previous
//
#include <hip/hip_runtime.h>
#include <hip/hip_bf16.h>

#define N_NODES 100000
#define N_EDGES 1600000
#define BN_EPS 1e-5f
#define SCAN_BLOCKS 391   // ceil(100000/256)

typedef __hip_bfloat16 bf16;
typedef unsigned long long ull;
typedef float v2f __attribute__((ext_vector_type(2)));
typedef short bfrag __attribute__((ext_vector_type(8)));   // 8 bf16 = 4 VGPRs
typedef float f32x4 __attribute__((ext_vector_type(4)));

__device__ __forceinline__ float b2f(bf16 v) { return __bfloat162float(v); }
__device__ __forceinline__ float frcp(float x) { return __builtin_amdgcn_rcpf(x); }
__device__ __forceinline__ float fsig(float x) { return frcp(1.0f + __expf(-x)); }
__device__ __forceinline__ float ftanh(float x) {
    return 1.0f - 2.0f * frcp(__expf(2.0f * x) + 1.0f);
}
__device__ __forceinline__ float bfr(uint u) { return __uint_as_float(u << 16); }
__device__ __forceinline__ v2f up(uint u) {
    return (v2f){__uint_as_float(u << 16), __uint_as_float(u & 0xffff0000u)};
}
__device__ __forceinline__ v2f vfma(v2f a, v2f b, v2f c) {
    return __builtin_elementwise_fma(a, b, c);
}
__device__ __forceinline__ uint pk2(const float* p) {
    bf16 a = __float2bfloat16(p[0]), b = __float2bfloat16(p[1]);
    return (uint)*(ushort*)&a | ((uint)*(ushort*)&b << 16);
}
__device__ __forceinline__ uint pkv(v2f v) {
    bf16 a = __float2bfloat16(v.x), b = __float2bfloat16(v.y);
    return (uint)*(ushort*)&a | ((uint)*(ushort*)&b << 16);
}
#define LDS_FENCE() __asm__ volatile("s_waitcnt lgkmcnt(0)" ::: "memory")

// ---- utility ---------------------------------------------------------------
__global__ void k_zero_f(float* __restrict__ p, int n) {
    int i = blockIdx.x * 256 + threadIdx.x;
    if (i < n) p[i] = 0.f;
}
__global__ void k_marker(float* __restrict__ p, int n, float v) {
    int i = blockIdx.x * 256 + threadIdx.x;
    if (i < n) p[i] = v;
}

// ---- packed histogram FUSED with A = x @ W1 --------------------------------
// hist is atomic-throughput-bound (21 G RMW/s, 1% VALU): the xw1 matmul's
// VALU + BW cost rides inside the atomic drain for free. Each of the 6250
// blocks handles 256 edges AND two 256-elem tiles of A (6250*512 = 3.2M).
__global__ __launch_bounds__(256) void k_hist(
    const int* __restrict__ ei, const float* __restrict__ ew,
    const float* __restrict__ x, const float* __restrict__ w1,
    ull* __restrict__ pk, int* __restrict__ rank, bf16* __restrict__ A) {
    __shared__ float Ws[32 * 33];
    __shared__ float xs[512];
    int tid = threadIdx.x;
    // issue the remote atomic first; everything below fills its shadow
    int e = blockIdx.x * 256 + tid;               // grid covers N_EDGES exactly
    int d = ei[N_EDGES + e];
    ull v = (1ull << 48) | (ull)((double)ew[e] * 4294967296.0);
    ull old = atomicAdd(&pk[d], v);
    // xw1 for 2 tiles
    for (int i = tid; i < 1024; i += 256)
        Ws[(i >> 5) * 33 + (i & 31)] = w1[i];
    long base = (long)blockIdx.x * 512;
    xs[tid] = x[base + tid];
    xs[256 + tid] = x[base + 256 + tid];
    __syncthreads();
    int r = tid >> 5, h = tid & 31;
    float acc0 = 0.f, acc1 = 0.f;
#pragma unroll
    for (int f = 0; f < 32; f++) {
        float wv = Ws[f * 33 + h];
        acc0 += xs[r * 32 + f] * wv;
        acc1 += xs[256 + r * 32 + f] * wv;
    }
    A[base + tid] = __float2bfloat16(acc0);
    A[base + 256 + tid] = __float2bfloat16(acc1);
    rank[e] = (int)(old >> 48);
}

// ---- scan stage 1 FUSED with column sums of x (for skip_avg) ---------------
__global__ void k_bsum(const ull* __restrict__ pk, int* __restrict__ bsum,
                       const float* __restrict__ x, float* __restrict__ xsum) {
    __shared__ int sc[256];
    __shared__ float sf[256];
    int tid = threadIdx.x;
    int idx = blockIdx.x * 256 + tid;
    sc[tid] = (idx < N_NODES) ? (int)(pk[idx] >> 48) : 0;
    int f = tid & 31, rg = tid >> 5;
    float acc = 0.f;
    for (int n = blockIdx.x * 8 + rg; n < N_NODES; n += SCAN_BLOCKS * 8)
        acc += x[n * 32 + f];
    sf[tid] = acc;
    __syncthreads();
    for (int st = 128; st >= 1; st >>= 1) {
        if (tid < st) {
            sc[tid] += sc[tid + st];
            if (st >= 32) sf[tid] += sf[tid + st];
        }
        __syncthreads();
    }
    if (tid == 0) bsum[blockIdx.x] = sc[0];
    if (tid < 32) atomicAdd(&xsum[tid], sf[tid]);
}

// ---- scan stage 2 (fused): block base via reduction + local scan -> off ----
// dinv[n] = rsqrt(deg_n + 1) stored instead of raw degree.
__global__ void k_scan3(const ull* __restrict__ pk, const int* __restrict__ bsum,
                        int* __restrict__ off, float* __restrict__ dinv) {
    __shared__ int red[256];
    __shared__ int wsum[4];
    int tid = threadIdx.x;
    int acc = 0;
    for (int i = tid; i < SCAN_BLOCKS; i += 256)
        if (i < blockIdx.x) acc += bsum[i];
    red[tid] = acc; __syncthreads();
    for (int st = 128; st >= 1; st >>= 1) {
        if (tid < st) red[tid] += red[tid + st];
        __syncthreads();
    }
    int bbase = red[0];
    int idx = blockIdx.x * 256 + tid;
    int lane = tid & 63, w = tid >> 6;
    ull pv = (idx < N_NODES) ? pk[idx] : 0ull;
    int c = (int)(pv >> 48);
    int s = c;
    for (int d = 1; d < 64; d <<= 1) {
        int u = __shfl_up(s, d, 64);
        if (lane >= d) s += u;
    }
    if (lane == 63) wsum[w] = s;
    __syncthreads();
    int wb = 0;
    for (int i = 0; i < w; i++) wb += wsum[i];
    int e = bbase + wb + s - c;                  // exclusive
    if (idx < N_NODES) {
        off[idx] = e;
        float degf = (float)((double)(pv & 0xFFFFFFFFFFFFull) * (1.0 / 4294967296.0));
        dinv[idx] = rsqrtf(degf + 1.0f);
    }
    if (idx == 0) off[N_NODES] = N_EDGES;        // all dst are in-range
}

// ---- scatter edges into CSR slots as {src, norm} — NO atomics --------------
__global__ void k_scatter(const int* __restrict__ ei, const float* __restrict__ ew,
                          const float* __restrict__ dinv, const int* __restrict__ off,
                          const int* __restrict__ rank, int2* __restrict__ epk) {
    int e = blockIdx.x * 256 + threadIdx.x;
    if (e < N_EDGES) {
        int s = ei[e], d = ei[N_EDGES + e];
        float nm = ew[e] * dinv[s] * dinv[d];
        epk[off[d] + rank[e]] = make_int2(s, __float_as_int(nm));
    }
}

// ---- pull-mode GCN: 4 lanes/node, uint4 (8-feature) gathers ----------------
// Each quad lane owns feature slice [8*fp, 8*fp+8). A 64-lane wave covers 16
// nodes; each of the 4 batched gather instructions has 16 distinct 64B lines
// in flight (64 lines/wave) -> high MLP for the latency-bound random gather.
// Tail edges folded into the batch via clamped index + zeroed norm.
__global__ __launch_bounds__(256) void k_gcn(
    const int* __restrict__ off, const int2* __restrict__ epk,
    const bf16* __restrict__ A, const float* __restrict__ dinv,
    const float* __restrict__ bias, bf16* __restrict__ B,
    float* __restrict__ sum, float* __restrict__ sq) {
    __shared__ float rS[4][4][8];
    __shared__ float rQ[4][4][8];
    const uint4* A4 = (const uint4*)A;
    uint4* B4 = (uint4*)B;
    int tid = threadIdx.x, fp = tid & 3, q = tid >> 2;
    int n = blockIdx.x * 64 + q;
    bool valid = n < N_NODES;

    v2f bv0 = (v2f){bias[8 * fp + 0], bias[8 * fp + 1]};
    v2f bv1 = (v2f){bias[8 * fp + 2], bias[8 * fp + 3]};
    v2f bv2 = (v2f){bias[8 * fp + 4], bias[8 * fp + 5]};
    v2f bv3 = (v2f){bias[8 * fp + 6], bias[8 * fp + 7]};

    v2f aA0 = (v2f)0.f, aA1 = (v2f)0.f, aA2 = (v2f)0.f, aA3 = (v2f)0.f;
    v2f aB0 = (v2f)0.f, aB1 = (v2f)0.f, aB2 = (v2f)0.f, aB3 = (v2f)0.f;

    int lo = 0, hi = 0;
    if (valid) { lo = off[n]; hi = off[n + 1]; }

    for (int p = lo; p < hi; p += 4) {
        int p1 = min(p + 1, hi - 1), p2 = min(p + 2, hi - 1), p3 = min(p + 3, hi - 1);
        int2 e0 = epk[p], e1 = epk[p1], e2 = epk[p2], e3 = epk[p3];
        float n0 = __int_as_float(e0.y);
        float n1 = (p + 1 < hi) ? __int_as_float(e1.y) : 0.f;
        float n2 = (p + 2 < hi) ? __int_as_float(e2.y) : 0.f;
        float n3 = (p + 3 < hi) ? __int_as_float(e3.y) : 0.f;
        uint4 g0 = A4[(long)e0.x * 4 + fp];
        uint4 g1 = A4[(long)e1.x * 4 + fp];
        uint4 g2 = A4[(long)e2.x * 4 + fp];
        uint4 g3 = A4[(long)e3.x * 4 + fp];
        v2f v0 = (v2f){n0, n0}, v1 = (v2f){n1, n1};
        v2f v2 = (v2f){n2, n2}, v3 = (v2f){n3, n3};
        aA0 = vfma(up(g0.x), v0, aA0); aA1 = vfma(up(g0.y), v0, aA1);
        aA2 = vfma(up(g0.z), v0, aA2); aA3 = vfma(up(g0.w), v0, aA3);
        aA0 = vfma(up(g1.x), v1, aA0); aA1 = vfma(up(g1.y), v1, aA1);
        aA2 = vfma(up(g1.z), v1, aA2); aA3 = vfma(up(g1.w), v1, aA3);
        aB0 = vfma(up(g2.x), v2, aB0); aB1 = vfma(up(g2.y), v2, aB1);
        aB2 = vfma(up(g2.z), v2, aB2); aB3 = vfma(up(g2.w), v2, aB3);
        aB0 = vfma(up(g3.x), v3, aB0); aB1 = vfma(up(g3.y), v3, aB1);
        aB2 = vfma(up(g3.z), v3, aB2); aB3 = vfma(up(g3.w), v3, aB3);
    }

    v2f bns0 = (v2f)0.f, bns1 = (v2f)0.f, bns2 = (v2f)0.f, bns3 = (v2f)0.f;
    v2f bnq0 = (v2f)0.f, bnq1 = (v2f)0.f, bnq2 = (v2f)0.f, bnq3 = (v2f)0.f;

    if (valid) {
        float dv = dinv[n];
        float si = dv * dv;                      // 1/(deg+1)
        v2f sv = (v2f){si, si};
        uint4 qs = A4[(long)n * 4 + fp];
        v2f o0 = vfma(up(qs.x), sv, aA0 + aB0) + bv0;
        v2f o1 = vfma(up(qs.y), sv, aA1 + aB1) + bv1;
        v2f o2 = vfma(up(qs.z), sv, aA2 + aB2) + bv2;
        v2f o3 = vfma(up(qs.w), sv, aA3 + aB3) + bv3;
        o0.x = fmaxf(o0.x, 0.f); o0.y = fmaxf(o0.y, 0.f);
        o1.x = fmaxf(o1.x, 0.f); o1.y = fmaxf(o1.y, 0.f);
        o2.x = fmaxf(o2.x, 0.f); o2.y = fmaxf(o2.y, 0.f);
        o3.x = fmaxf(o3.x, 0.f); o3.y = fmaxf(o3.y, 0.f);
        uint4 ov = make_uint4(pkv(o0), pkv(o1), pkv(o2), pkv(o3));
        B4[(long)n * 4 + fp] = ov;
        bns0 = o0; bns1 = o1; bns2 = o2; bns3 = o3;
        bnq0 = o0 * o0; bnq1 = o1 * o1; bnq2 = o2 * o2; bnq3 = o3 * o3;
    }

    // wave-level reduce across quads (lanes with same fp share a feat slice)
#pragma unroll
    for (int st = 4; st <= 32; st <<= 1) {
        bns0.x += __shfl_xor(bns0.x, st); bns0.y += __shfl_xor(bns0.y, st);
        bns1.x += __shfl_xor(bns1.x, st); bns1.y += __shfl_xor(bns1.y, st);
        bns2.x += __shfl_xor(bns2.x, st); bns2.y += __shfl_xor(bns2.y, st);
        bns3.x += __shfl_xor(bns3.x, st); bns3.y += __shfl_xor(bns3.y, st);
        bnq0.x += __shfl_xor(bnq0.x, st); bnq0.y += __shfl_xor(bnq0.y, st);
        bnq1.x += __shfl_xor(bnq1.x, st); bnq1.y += __shfl_xor(bnq1.y, st);
        bnq2.x += __shfl_xor(bnq2.x, st); bnq2.y += __shfl_xor(bnq2.y, st);
        bnq3.x += __shfl_xor(bnq3.x, st); bnq3.y += __shfl_xor(bnq3.y, st);
    }
    int lane = tid & 63, wv = tid >> 6;
    if (lane < 4) {
        rS[wv][lane][0] = bns0.x; rS[wv][lane][1] = bns0.y;
        rS[wv][lane][2] = bns1.x; rS[wv][lane][3] = bns1.y;
        rS[wv][lane][4] = bns2.x; rS[wv][lane][5] = bns2.y;
        rS[wv][lane][6] = bns3.x; rS[wv][lane][7] = bns3.y;
        rQ[wv][lane][0] = bnq0.x; rQ[wv][lane][1] = bnq0.y;
        rQ[wv][lane][2] = bnq1.x; rQ[wv][lane][3] = bnq1.y;
        rQ[wv][lane][4] = bnq2.x; rQ[wv][lane][5] = bnq2.y;
        rQ[wv][lane][6] = bnq3.x; rQ[wv][lane][7] = bnq3.y;
    }
    __syncthreads();
    if (tid < 32) {
        float ts = 0.f, tq = 0.f;
#pragma unroll
        for (int w = 0; w < 4; w++) {
            ts += rS[w][tid >> 3][tid & 7];
            tq += rQ[w][tid >> 3][tid & 7];
        }
        atomicAdd(&sum[tid], ts);
        atomicAdd(&sq[tid], tq);
    }
}

// ---- H = affine(B) (bf16); A = H @ W2 (bf16); BN1 finalize fused -----------
__global__ void k_aff_xw(const bf16* __restrict__ B, const float* __restrict__ sum,
                         const float* __restrict__ sq, const float* __restrict__ g,
                         const float* __restrict__ be, const float* __restrict__ w,
                         bf16* __restrict__ H, bf16* __restrict__ A) {
    __shared__ float Ws[32 * 33];
    __shared__ float hs[256];
    __shared__ float sc[32], sh[32];
    int tid = threadIdx.x;
    if (tid < 32) {
        float mu = sum[tid] / (float)N_NODES;
        float var = sq[tid] / (float)N_NODES - mu * mu;
        float rs = rsqrtf(var + BN_EPS) * g[tid];
        sc[tid] = rs;
        sh[tid] = be[tid] - mu * rs;
    }
    for (int i = tid; i < 1024; i += 256)
        Ws[(i >> 5) * 33 + (i & 31)] = w[i];
    __syncthreads();
    long base = (long)blockIdx.x * 256;
    int f = tid & 31;
    float h = b2f(B[base + tid]) * sc[f] + sh[f];
    H[base + tid] = __float2bfloat16(h);
    hs[tid] = h;
    __syncthreads();
    int r = tid >> 5, hc = tid & 31;
    float acc = 0.f;
#pragma unroll
    for (int k = 0; k < 32; k++) acc += hs[r * 32 + k] * Ws[k * 33 + hc];
    A[base + tid] = __float2bfloat16(acc);
}

// ---- per-node dense stack via MFMA; BN2/fc1-const/bias finalize fused ------
// 128 nodes/block, 4 waves, each wave owns 2 disjoint 16-node M-tiles.
// Layouts (verified): A[m=lane&15][k=quad*8+j], B[k=quad*8+j][n=lane&15],
// C/D[row=quad*4+r][col=lane&15].
#define CATP 72
#define WP1  72
#define WP2  40
#define FP1  72
#define HP   40
__global__ __launch_bounds__(256) void k_final(
    const bf16* __restrict__ Hb, const bf16* __restrict__ Bb,
    const float* __restrict__ bn2sum, const float* __restrict__ bn2sq,
    const float* __restrict__ g2, const float* __restrict__ be2,
    const float* __restrict__ xsum,
    const float* __restrict__ wih1, const float* __restrict__ wih2,
    const float* __restrict__ fw1, const float* __restrict__ fw2,
    const float* __restrict__ fb2, const float* __restrict__ fb1,
    const float* __restrict__ bih1, const float* __restrict__ bhh1,
    const float* __restrict__ bih2, const float* __restrict__ bhh2,
    float* __restrict__ out) {
    __shared__ ushort cat[128 * CATP];
    __shared__ ushort W1s[96 * WP1];
    __shared__ ushort W2s[96 * WP2];
    __shared__ ushort F1s[32 * FP1];
    __shared__ ushort h1s[128 * HP];
    __shared__ ushort h2s[128 * HP];
    __shared__ float lb1s[128], lb2s[128], fc1s[32], fw2s[32], sc2[32], sh2[32];
    int tid = threadIdx.x;
    if (tid < 128) { lb1s[tid] = bih1[tid] + bhh1[tid]; lb2s[tid] = bih2[tid] + bhh2[tid]; }
    if (tid >= 128 && tid < 160) {
        int t = tid - 128;
        float mu = bn2sum[t] / (float)N_NODES;
        float var = bn2sq[t] / (float)N_NODES - mu * mu;
        float rs = rsqrtf(var + BN_EPS) * g2[t];
        sc2[t] = rs;
        sh2[t] = be2[t] - mu * rs;
        fw2s[t] = fw2[t];
        float c = fb1[t];
        for (int f = 0; f < 32; f++)
            c += (xsum[f] / (float)N_NODES) * fw1[t * 96 + 64 + f];
        fc1s[t] = c;
    }
    // W1s rows = gate-cols n: 0..31 -> wih1 row n (i), 32..63 -> 64+(n-32) (g),
    // 64..95 -> 96+(n-64) (o). Same mapping for W2s/wih2.
    for (int i = tid; i < 96 * 8; i += 256) {
        int row = i >> 3, q = i & 7;
        int c = row & 31, t = row >> 5;
        int srow = (t == 0) ? c : ((t == 1) ? 64 + c : 96 + c);
        const float* b = wih1 + srow * 64 + q * 8;
        *(uint4*)&W1s[row * WP1 + q * 8] =
            make_uint4(pk2(b), pk2(b + 2), pk2(b + 4), pk2(b + 6));
    }
    for (int i = tid; i < 96 * 4; i += 256) {
        int row = i >> 2, q = i & 3;
        int c = row & 31, t = row >> 5;
        int srow = (t == 0) ? c : ((t == 1) ? 64 + c : 96 + c);
        const float* b = wih2 + srow * 32 + q * 8;
        *(uint4*)&W2s[row * WP2 + q * 8] =
            make_uint4(pk2(b), pk2(b + 2), pk2(b + 4), pk2(b + 6));
    }
    for (int i = tid; i < 32 * 8; i += 256) {
        int row = i >> 3, q = i & 7;
        const float* b = fw1 + row * 96 + q * 8;
        *(uint4*)&F1s[row * FP1 + q * 8] =
            make_uint4(pk2(b), pk2(b + 2), pk2(b + 4), pk2(b + 6));
    }
    __syncthreads();
    // ---- stage cat[node][0..63] = [H | affine(B)] --------------------------
    {
        int ni = tid >> 1, hf = tid & 1;
        int node = blockIdx.x * 128 + ni;
        int nc = node < N_NODES ? node : N_NODES - 1;
        const uint4* src = (const uint4*)((const ushort*)(hf ? Bb : Hb) + (long)nc * 32);
        ushort* dst = &cat[ni * CATP + hf * 32];
        if (hf == 0) {
#pragma unroll
            for (int q = 0; q < 4; q++) *(uint4*)(dst + q * 8) = src[q];
        } else {
#pragma unroll
            for (int q = 0; q < 4; q++) {
                uint4 v = src[q];
                uint w[4] = {v.x, v.y, v.z, v.w};
                uint o[4];
#pragma unroll
                for (int r = 0; r < 4; r++) {
                    int e = q * 8 + r * 2;
                    o[r] = pkv(vfma(up(w[r]), (v2f){sc2[e], sc2[e + 1]},
                                    (v2f){sh2[e], sh2[e + 1]}));
                }
                *(uint4*)(dst + q * 8) = make_uint4(o[0], o[1], o[2], o[3]);
            }
        }
    }
    __syncthreads();
    // ---- compute: wave wv owns M-tiles wv*2, wv*2+1 ------------------------
    int l = tid & 63, wv = tid >> 6;
    int quad = l >> 4, mr = l & 15;
    float fb2v = fb2[0];
#pragma unroll
    for (int it = 0; it < 2; it++) {
        int mt = wv * 2 + it;
        int mb = mt * 16;
        // LSTM1 gates
        bfrag a0 = *(const bfrag*)&cat[(mb + mr) * CATP + quad * 8];
        bfrag a1 = *(const bfrag*)&cat[(mb + mr) * CATP + 32 + quad * 8];
        f32x4 g[6];
#pragma unroll
        for (int nt = 0; nt < 6; nt++) {
            bfrag b0 = *(const bfrag*)&W1s[(nt * 16 + mr) * WP1 + quad * 8];
            bfrag b1 = *(const bfrag*)&W1s[(nt * 16 + mr) * WP1 + 32 + quad * 8];
            f32x4 z = {0.f, 0.f, 0.f, 0.f};
            z = __builtin_amdgcn_mfma_f32_16x16x32_bf16(a0, b0, z, 0, 0, 0);
            z = __builtin_amdgcn_mfma_f32_16x16x32_bf16(a1, b1, z, 0, 0, 0);
            g[nt] = z;
        }
#pragma unroll
        for (int t = 0; t < 2; t++) {
            int c = t * 16 + mr;
            float bi = lb1s[c], bg = lb1s[64 + c], bo = lb1s[96 + c];
#pragma unroll
            for (int r = 0; r < 4; r++) {
                float c1 = fsig(g[t][r] + bi) * ftanh(g[2 + t][r] + bg);
                float h = fsig(g[4 + t][r] + bo) * ftanh(c1);
                bf16 hb = __float2bfloat16(h);
                h1s[(mb + quad * 4 + r) * HP + c] = *(ushort*)&hb;
            }
        }
        LDS_FENCE();
        // LSTM2 gates
        bfrag ha = *(const bfrag*)&h1s[(mb + mr) * HP + quad * 8];
        f32x4 g2r[6];
#pragma unroll
        for (int nt = 0; nt < 6; nt++) {
            bfrag b = *(const bfrag*)&W2s[(nt * 16 + mr) * WP2 + quad * 8];
            f32x4 z = {0.f, 0.f, 0.f, 0.f};
            z = __builtin_amdgcn_mfma_f32_16x16x32_bf16(ha, b, z, 0, 0, 0);
            g2r[nt] = z;
        }
#pragma unroll
        for (int t = 0; t < 2; t++) {
            int c = t * 16 + mr;
            float bi = lb2s[c], bg = lb2s[64 + c], bo = lb2s[96 + c];
#pragma unroll
            for (int r = 0; r < 4; r++) {
                float c2 = fsig(g2r[t][r] + bi) * ftanh(g2r[2 + t][r] + bg);
                float h = fsig(g2r[4 + t][r] + bo) * ftanh(c2);
                bf16 hb = __float2bfloat16(h);
                h2s[(mb + quad * 4 + r) * HP + c] = *(ushort*)&hb;
            }
        }
        LDS_FENCE();
        // fc1 (K=32 from hn1 via F1 cols 0..31, K=32 from hn2 via cols 32..63)
        bfrag hb2 = *(const bfrag*)&h2s[(mb + mr) * HP + quad * 8];
        f32x4 zt[2];
#pragma unroll
        for (int nt = 0; nt < 2; nt++) {
            bfrag f0 = *(const bfrag*)&F1s[(nt * 16 + mr) * FP1 + quad * 8];
            bfrag f1 = *(const bfrag*)&F1s[(nt * 16 + mr) * FP1 + 32 + quad * 8];
            f32x4 z = {0.f, 0.f, 0.f, 0.f};
            z = __builtin_amdgcn_mfma_f32_16x16x32_bf16(ha, f0, z, 0, 0, 0);
            z = __builtin_amdgcn_mfma_f32_16x16x32_bf16(hb2, f1, z, 0, 0, 0);
            zt[nt] = z;
        }
        // epilogue: relu(z + fc1c) . fw2, reduce over 32 cols
#pragma unroll
        for (int r = 0; r < 4; r++) {
            float s = 0.f;
#pragma unroll
            for (int t = 0; t < 2; t++) {
                int j = t * 16 + mr;
                s += fmaxf(zt[t][r] + fc1s[j], 0.f) * fw2s[j];
            }
            s += __shfl_xor(s, 1); s += __shfl_xor(s, 2);
            s += __shfl_xor(s, 4); s += __shfl_xor(s, 8);
            int node = blockIdx.x * 128 + mb + quad * 4 + r;
            if (mr == 0 && node < N_NODES) out[node] = s + fb2v;
        }
    }
}

extern "C" void kernel_launch(void* const* d_in, const int* in_sizes, int n_in,
                              void* d_out, int out_size, void* d_ws, size_t ws_size,
                              hipStream_t stream) {
    const float* x    = (const float*)d_in[0];
    const int*   ei   = (const int*)d_in[1];
    const float* ew   = (const float*)d_in[2];
    const float* w1   = (const float*)d_in[3];
    const float* b1   = (const float*)d_in[4];
    const float* g1   = (const float*)d_in[5];
    const float* be1  = (const float*)d_in[6];
    const float* w2   = (const float*)d_in[7];
    const float* b2   = (const float*)d_in[8];
    const float* g2   = (const float*)d_in[9];
    const float* be2  = (const float*)d_in[10];
    const float* wih1 = (const float*)d_in[11];
    const float* bih1 = (const float*)d_in[13];
    const float* bhh1 = (const float*)d_in[14];
    const float* wih2 = (const float*)d_in[15];
    const float* bih2 = (const float*)d_in[17];
    const float* bhh2 = (const float*)d_in[18];
    const float* fw1  = (const float*)d_in[19];
    const float* fb1  = (const float*)d_in[20];
    const float* fw2  = (const float*)d_in[21];
    const float* fb2  = (const float*)d_in[22];
    float* out = (float*)d_out;

    // ---- workspace layout (40.5 MB; proven ws >= 41.1 MB from r3/r4) -------
    char* ws = (char*)d_ws;
    float* stats = (float*)ws;                          // 160 floats used
    float* xsum   = stats + 0;
    float* bn1sum = stats + 32;
    float* bn1sq  = stats + 64;
    float* bn2sum = stats + 96;
    float* bn2sq  = stats + 128;
    ull*   pk    = (ull*)  (ws + 4096);                 // 100000 ull -> 804,096
    int*   bsum  = (int*)  (ws + 804096);               // 391 i
    int*   off   = (int*)  (ws + 1048576);              // 100001 i -> 1,448,580
    float* dinv  = (float*)(ws + 1572864);              // 100000 f -> 1,972,864
    int2*  epk   = (int2*) (ws + 2097152);              // 1.6M int2 -> 14,897,152
    int*   rank  = (int*)  (ws + 14897152);             // 1.6M i -> 21,297,152
    bf16*  A     = (bf16*) (ws + 21297152);             // 6.4MB -> 27,697,152
    bf16*  H     = (bf16*) (ws + 27697152);             // 6.4MB -> 34,097,152
    bf16*  B     = (bf16*) (ws + 34097152);             // 6.4MB -> 40,497,152

    if (ws_size < 40497152ull) {
        k_marker<<<(N_NODES + 255) / 256, 256, 0, stream>>>(out, N_NODES, 911.f);
        return;
    }

    // zero stats + pk in one shot (bytes 0 .. 804,096)
    k_zero_f<<<786, 256, 0, stream>>>(stats, 201024);

    k_hist<<<6250, 256, 0, stream>>>(ei, ew, x, w1, pk, rank, A);
    k_bsum<<<SCAN_BLOCKS, 256, 0, stream>>>(pk, bsum, x, xsum);
    k_scan3<<<SCAN_BLOCKS, 256, 0, stream>>>(pk, bsum, off, dinv);
    k_scatter<<<6250, 256, 0, stream>>>(ei, ew, dinv, off, rank, epk);
    k_gcn<<<1563, 256, 0, stream>>>(off, epk, A, dinv, b1, B, bn1sum, bn1sq);
    k_aff_xw<<<12500, 256, 0, stream>>>(B, bn1sum, bn1sq, g1, be1, w2, H, A);
    k_gcn<<<1563, 256, 0, stream>>>(off, epk, A, dinv, b2, B, bn2sum, bn2sq);
    k_final<<<782, 256, 0, stream>>>(H, B, bn2sum, bn2sq, g2, be2, xsum,
                                     wih1, wih2, fw1, fw2, fb2, fb1,
                                     bih1, bhh1, bih2, bhh2, out);
}

// Round 3
// 328.038 us; speedup vs baseline: 1.3651x; 1.0971x over previous
//
#include <hip/hip_runtime.h>
#include <hip/hip_bf16.h>

#define N_NODES 100000
#define N_EDGES 1600000
#define BN_EPS 1e-5f
#define NCB  391    // coarse buckets = ceil(100000/256), bucket = dst>>8
#define NBLK 782    // edge blocks, 2048 edges each (782*2048 >= 1.6M)
#define EPB  2048
#define CAP  4608   // LDS staging capacity per fine bucket (avg 4092, ~8 sigma)

typedef __hip_bfloat16 bf16;
typedef unsigned long long ull;
typedef float v2f __attribute__((ext_vector_type(2)));
typedef short bfrag __attribute__((ext_vector_type(8)));   // 8 bf16 = 4 VGPRs
typedef float f32x4 __attribute__((ext_vector_type(4)));

__device__ __forceinline__ float b2f(bf16 v) { return __bfloat162float(v); }
__device__ __forceinline__ float frcp(float x) { return __builtin_amdgcn_rcpf(x); }
__device__ __forceinline__ float fsig(float x) { return frcp(1.0f + __expf(-x)); }
__device__ __forceinline__ float ftanh(float x) {
    return 1.0f - 2.0f * frcp(__expf(2.0f * x) + 1.0f);
}
__device__ __forceinline__ v2f up(uint u) {
    return (v2f){__uint_as_float(u << 16), __uint_as_float(u & 0xffff0000u)};
}
__device__ __forceinline__ v2f vfma(v2f a, v2f b, v2f c) {
    return __builtin_elementwise_fma(a, b, c);
}
__device__ __forceinline__ uint pk2(const float* p) {
    bf16 a = __float2bfloat16(p[0]), b = __float2bfloat16(p[1]);
    return (uint)*(ushort*)&a | ((uint)*(ushort*)&b << 16);
}
__device__ __forceinline__ uint pkv(v2f v) {
    bf16 a = __float2bfloat16(v.x), b = __float2bfloat16(v.y);
    return (uint)*(ushort*)&a | ((uint)*(ushort*)&b << 16);
}
#define LDS_FENCE() __asm__ volatile("s_waitcnt lgkmcnt(0)" ::: "memory")

// block-wide (256 thr) exclusive scan; wsum = LDS int[4]; total broadcast
__device__ __forceinline__ int blk_exscan(int v, int tid, int* wsum, int* total) {
    int lane = tid & 63, w = tid >> 6;
    int s = v;
    for (int d = 1; d < 64; d <<= 1) {
        int u = __shfl_up(s, d, 64);
        if (lane >= d) s += u;
    }
    if (lane == 63) wsum[w] = s;
    __syncthreads();
    int wb = 0;
    for (int i = 0; i < w; i++) wb += wsum[i];
    int tot = wsum[0] + wsum[1] + wsum[2] + wsum[3];
    __syncthreads();            // wsum reusable by next call
    *total = tot;
    return wb + s - v;
}

// ---- utility ---------------------------------------------------------------
__global__ void k_zero_s(float* __restrict__ p) {
    if (threadIdx.x < 192) p[threadIdx.x] = 0.f;
}
__global__ void k_marker(float* __restrict__ p, int n, float v) {
    int i = blockIdx.x * 256 + threadIdx.x;
    if (i < n) p[i] = v;
}

// ---- P1: per-block coarse histogram (LDS atomics only) + A = x @ W1 --------
__global__ __launch_bounds__(256) void k_count(
    const int* __restrict__ ei, const float* __restrict__ x,
    const float* __restrict__ w1, int* __restrict__ ghist,
    bf16* __restrict__ A) {
    __shared__ int hist[NCB];
    __shared__ float Ws[32 * 33];
    __shared__ float xs[512];
    int tid = threadIdx.x, blk = blockIdx.x;
    for (int i = tid; i < NCB; i += 256) hist[i] = 0;
    for (int i = tid; i < 1024; i += 256)
        Ws[(i >> 5) * 33 + (i & 31)] = w1[i];
    __syncthreads();
#pragma unroll
    for (int k = 0; k < 8; k++) {
        int e = blk * EPB + k * 256 + tid;
        if (e < N_EDGES) atomicAdd(&hist[ei[N_EDGES + e] >> 8], 1);
    }
    // xw1: this block covers 4096 x-elems (782*4096 = 3,203,072 > 3.2M: guard)
    for (int g = 0; g < 8; g++) {
        long base = (long)blk * 4096 + g * 512;
        xs[tid] = (base + tid < (long)N_NODES * 32) ? x[base + tid] : 0.f;
        xs[256 + tid] = (base + 256 + tid < (long)N_NODES * 32) ? x[base + 256 + tid] : 0.f;
        __syncthreads();
        int r = tid >> 5, h = tid & 31;
        float acc0 = 0.f, acc1 = 0.f;
#pragma unroll
        for (int f = 0; f < 32; f++) {
            float wv = Ws[f * 33 + h];
            acc0 += xs[r * 32 + f] * wv;
            acc1 += xs[256 + r * 32 + f] * wv;
        }
        if (base + tid < (long)N_NODES * 32) A[base + tid] = __float2bfloat16(acc0);
        if (base + 256 + tid < (long)N_NODES * 32) A[base + 256 + tid] = __float2bfloat16(acc1);
        __syncthreads();
    }
    for (int i = tid; i < NCB; i += 256) ghist[(long)i * NBLK + blk] = hist[i];
}

// ---- P2a: bucket totals (row sums) + column sums of x (skip_avg) -----------
__global__ void k_tot(const int* __restrict__ ghist, int* __restrict__ tot,
                      const float* __restrict__ x, float* __restrict__ xsum) {
    __shared__ int sc[256];
    __shared__ float sf[256];
    int tid = threadIdx.x, b = blockIdx.x;
    const int* row = ghist + (long)b * NBLK;
    int acc = 0;
    for (int i = tid; i < NBLK; i += 256) acc += row[i];
    sc[tid] = acc;
    int f = tid & 31, rg = tid >> 5;
    float accf = 0.f;
    for (int n = b * 8 + rg; n < N_NODES; n += NCB * 8)
        accf += x[n * 32 + f];
    sf[tid] = accf;
    __syncthreads();
    for (int st = 128; st >= 1; st >>= 1) {
        if (tid < st) {
            sc[tid] += sc[tid + st];
            if (st >= 32) sf[tid] += sf[tid + st];
        }
        __syncthreads();
    }
    if (tid == 0) tot[b] = sc[0];
    if (tid < 32) atomicAdd(&xsum[tid], sf[tid]);
}

// ---- P2b: exclusive scan of bucket totals -> cbase[0..391] -----------------
__global__ void k_base(const int* __restrict__ tot, int* __restrict__ cbase) {
    __shared__ int wsum[4];
    __shared__ int carry;
    int tid = threadIdx.x;
    if (tid == 0) carry = 0;
    __syncthreads();
    for (int r = 0; r < 2; r++) {
        int idx = r * 256 + tid;
        int v = (idx < NCB) ? tot[idx] : 0;
        int T;
        int ex = blk_exscan(v, tid, wsum, &T);
        int c = carry;
        if (idx < NCB + 1) cbase[idx] = c + ex;
        __syncthreads();
        if (tid == 0) carry = c + T;
        __syncthreads();
    }
}

// ---- P2c: per-bucket row scan -> gbase (in-place over ghist) ---------------
__global__ void k_rowscan(int* __restrict__ ghist, const int* __restrict__ cbase) {
    __shared__ int wsum[4];
    __shared__ int carry;
    int tid = threadIdx.x, b = blockIdx.x;
    int* row = ghist + (long)b * NBLK;
    int base = cbase[b];
    if (tid == 0) carry = 0;
    __syncthreads();
    for (int r = 0; r < 4; r++) {
        int idx = r * 256 + tid;
        int v = (idx < NBLK) ? row[idx] : 0;
        int T;
        int ex = blk_exscan(v, tid, wsum, &T);
        int c = carry;
        if (idx < NBLK) row[idx] = base + c + ex;
        __syncthreads();
        if (tid == 0) carry = c + T;
        __syncthreads();
    }
}

// ---- P3: coarse scatter into bucket segments (no global atomics) -----------
// cse[pos] = { src | dlow<<17 , ew }  (src < 2^17, dlow 8 bits)
__global__ __launch_bounds__(256) void k_cscatter(
    const int* __restrict__ ei, const float* __restrict__ ew,
    const int* __restrict__ gbase, int2* __restrict__ cse) {
    __shared__ int cnt[NCB];
    __shared__ int cur[NCB];
    int tid = threadIdx.x, blk = blockIdx.x;
    for (int i = tid; i < NCB; i += 256) {
        cnt[i] = 0;
        cur[i] = gbase[(long)i * NBLK + blk];
    }
    __syncthreads();
#pragma unroll
    for (int k = 0; k < 8; k++) {
        int e = blk * EPB + k * 256 + tid;
        if (e < N_EDGES) {
            int d = ei[N_EDGES + e];
            int b = d >> 8;
            int r = atomicAdd(&cnt[b], 1);
            cse[cur[b] + r] = make_int2(ei[e] | ((d & 255) << 17),
                                        __float_as_int(ew[e]));
        }
    }
}

// ---- P4: fine pass per bucket: counts, deg->dinv, off, coalesced epk -------
// epk[slot] = { src, ew * dinv[dst] }   (dinv[src] applied in P5)
__global__ __launch_bounds__(256) void k_fine(
    const int2* __restrict__ cse, const int* __restrict__ cbase,
    int2* __restrict__ epk, int* __restrict__ off, float* __restrict__ dinv) {
    __shared__ int2 outL[CAP];
    __shared__ int cnt[256];
    __shared__ float degw[256];
    __shared__ int cur[256];
    __shared__ int wsum[4];
    int tid = threadIdx.x, b = blockIdx.x;
    int s0 = cbase[b], s1 = cbase[b + 1];
    int segn = s1 - s0;
    cnt[tid] = 0;
    degw[tid] = 0.f;
    __syncthreads();
    for (int p = s0 + tid; p < s1; p += 256) {
        int2 v = cse[p];
        int dl = (v.x >> 17) & 255;
        atomicAdd(&cnt[dl], 1);
        atomicAdd(&degw[dl], __int_as_float(v.y));
    }
    __syncthreads();
    int T;
    int lofs = blk_exscan(cnt[tid], tid, wsum, &T);
    int nn = min(256, N_NODES - b * 256);
    float dv = rsqrtf(degw[tid] + 1.0f);
    if (tid < nn) {
        dinv[b * 256 + tid] = dv;
        off[b * 256 + tid] = s0 + lofs;
    }
    if (b == 0 && tid == 0) off[N_NODES] = N_EDGES;
    cur[tid] = lofs;
    __syncthreads();
    degw[tid] = dv;               // reuse as dinv[dlow] table
    __syncthreads();
    bool staged = segn <= CAP;
    for (int p = s0 + tid; p < s1; p += 256) {
        int2 v = cse[p];
        int dl = (v.x >> 17) & 255;
        int slot = atomicAdd(&cur[dl], 1);
        int2 o = make_int2(v.x & 0x1FFFF,
                           __float_as_int(__int_as_float(v.y) * degw[dl]));
        if (staged) outL[slot] = o;
        else epk[s0 + slot] = o;
    }
    __syncthreads();
    if (staged)
        for (int p = tid; p < segn; p += 256) epk[s0 + p] = outL[p];
}

// ---- P5: epk.y *= dinv[src] (sequential rw, L2-resident gather) ------------
__global__ void k_norm(int2* __restrict__ epk, const float* __restrict__ dinv) {
    int e = blockIdx.x * 256 + threadIdx.x;
    int2 v = epk[e];
    epk[e] = make_int2(v.x, __float_as_int(__int_as_float(v.y) * dinv[v.x]));
}

// ---- pull-mode GCN: 4 lanes/node, uint4 (8-feature) gathers ----------------
__global__ __launch_bounds__(256) void k_gcn(
    const int* __restrict__ off, const int2* __restrict__ epk,
    const bf16* __restrict__ A, const float* __restrict__ dinv,
    const float* __restrict__ bias, bf16* __restrict__ B,
    float* __restrict__ sum, float* __restrict__ sq) {
    __shared__ float rS[4][4][8];
    __shared__ float rQ[4][4][8];
    const uint4* A4 = (const uint4*)A;
    uint4* B4 = (uint4*)B;
    int tid = threadIdx.x, fp = tid & 3, q = tid >> 2;
    int n = blockIdx.x * 64 + q;
    bool valid = n < N_NODES;

    v2f bv0 = (v2f){bias[8 * fp + 0], bias[8 * fp + 1]};
    v2f bv1 = (v2f){bias[8 * fp + 2], bias[8 * fp + 3]};
    v2f bv2 = (v2f){bias[8 * fp + 4], bias[8 * fp + 5]};
    v2f bv3 = (v2f){bias[8 * fp + 6], bias[8 * fp + 7]};

    v2f aA0 = (v2f)0.f, aA1 = (v2f)0.f, aA2 = (v2f)0.f, aA3 = (v2f)0.f;
    v2f aB0 = (v2f)0.f, aB1 = (v2f)0.f, aB2 = (v2f)0.f, aB3 = (v2f)0.f;

    int lo = 0, hi = 0;
    if (valid) { lo = off[n]; hi = off[n + 1]; }

    for (int p = lo; p < hi; p += 4) {
        int p1 = min(p + 1, hi - 1), p2 = min(p + 2, hi - 1), p3 = min(p + 3, hi - 1);
        int2 e0 = epk[p], e1 = epk[p1], e2 = epk[p2], e3 = epk[p3];
        float n0 = __int_as_float(e0.y);
        float n1 = (p + 1 < hi) ? __int_as_float(e1.y) : 0.f;
        float n2 = (p + 2 < hi) ? __int_as_float(e2.y) : 0.f;
        float n3 = (p + 3 < hi) ? __int_as_float(e3.y) : 0.f;
        uint4 g0 = A4[(long)e0.x * 4 + fp];
        uint4 g1 = A4[(long)e1.x * 4 + fp];
        uint4 g2 = A4[(long)e2.x * 4 + fp];
        uint4 g3 = A4[(long)e3.x * 4 + fp];
        v2f v0 = (v2f){n0, n0}, v1 = (v2f){n1, n1};
        v2f v2 = (v2f){n2, n2}, v3 = (v2f){n3, n3};
        aA0 = vfma(up(g0.x), v0, aA0); aA1 = vfma(up(g0.y), v0, aA1);
        aA2 = vfma(up(g0.z), v0, aA2); aA3 = vfma(up(g0.w), v0, aA3);
        aA0 = vfma(up(g1.x), v1, aA0); aA1 = vfma(up(g1.y), v1, aA1);
        aA2 = vfma(up(g1.z), v1, aA2); aA3 = vfma(up(g1.w), v1, aA3);
        aB0 = vfma(up(g2.x), v2, aB0); aB1 = vfma(up(g2.y), v2, aB1);
        aB2 = vfma(up(g2.z), v2, aB2); aB3 = vfma(up(g2.w), v2, aB3);
        aB0 = vfma(up(g3.x), v3, aB0); aB1 = vfma(up(g3.y), v3, aB1);
        aB2 = vfma(up(g3.z), v3, aB2); aB3 = vfma(up(g3.w), v3, aB3);
    }

    v2f bns0 = (v2f)0.f, bns1 = (v2f)0.f, bns2 = (v2f)0.f, bns3 = (v2f)0.f;
    v2f bnq0 = (v2f)0.f, bnq1 = (v2f)0.f, bnq2 = (v2f)0.f, bnq3 = (v2f)0.f;

    if (valid) {
        float dv = dinv[n];
        float si = dv * dv;                      // 1/(deg+1)
        v2f sv = (v2f){si, si};
        uint4 qs = A4[(long)n * 4 + fp];
        v2f o0 = vfma(up(qs.x), sv, aA0 + aB0) + bv0;
        v2f o1 = vfma(up(qs.y), sv, aA1 + aB1) + bv1;
        v2f o2 = vfma(up(qs.z), sv, aA2 + aB2) + bv2;
        v2f o3 = vfma(up(qs.w), sv, aA3 + aB3) + bv3;
        o0.x = fmaxf(o0.x, 0.f); o0.y = fmaxf(o0.y, 0.f);
        o1.x = fmaxf(o1.x, 0.f); o1.y = fmaxf(o1.y, 0.f);
        o2.x = fmaxf(o2.x, 0.f); o2.y = fmaxf(o2.y, 0.f);
        o3.x = fmaxf(o3.x, 0.f); o3.y = fmaxf(o3.y, 0.f);
        uint4 ov = make_uint4(pkv(o0), pkv(o1), pkv(o2), pkv(o3));
        B4[(long)n * 4 + fp] = ov;
        bns0 = o0; bns1 = o1; bns2 = o2; bns3 = o3;
        bnq0 = o0 * o0; bnq1 = o1 * o1; bnq2 = o2 * o2; bnq3 = o3 * o3;
    }

#pragma unroll
    for (int st = 4; st <= 32; st <<= 1) {
        bns0.x += __shfl_xor(bns0.x, st); bns0.y += __shfl_xor(bns0.y, st);
        bns1.x += __shfl_xor(bns1.x, st); bns1.y += __shfl_xor(bns1.y, st);
        bns2.x += __shfl_xor(bns2.x, st); bns2.y += __shfl_xor(bns2.y, st);
        bns3.x += __shfl_xor(bns3.x, st); bns3.y += __shfl_xor(bns3.y, st);
        bnq0.x += __shfl_xor(bnq0.x, st); bnq0.y += __shfl_xor(bnq0.y, st);
        bnq1.x += __shfl_xor(bnq1.x, st); bnq1.y += __shfl_xor(bnq1.y, st);
        bnq2.x += __shfl_xor(bnq2.x, st); bnq2.y += __shfl_xor(bnq2.y, st);
        bnq3.x += __shfl_xor(bnq3.x, st); bnq3.y += __shfl_xor(bnq3.y, st);
    }
    int lane = tid & 63, wv = tid >> 6;
    if (lane < 4) {
        rS[wv][lane][0] = bns0.x; rS[wv][lane][1] = bns0.y;
        rS[wv][lane][2] = bns1.x; rS[wv][lane][3] = bns1.y;
        rS[wv][lane][4] = bns2.x; rS[wv][lane][5] = bns2.y;
        rS[wv][lane][6] = bns3.x; rS[wv][lane][7] = bns3.y;
        rQ[wv][lane][0] = bnq0.x; rQ[wv][lane][1] = bnq0.y;
        rQ[wv][lane][2] = bnq1.x; rQ[wv][lane][3] = bnq1.y;
        rQ[wv][lane][4] = bnq2.x; rQ[wv][lane][5] = bnq2.y;
        rQ[wv][lane][6] = bnq3.x; rQ[wv][lane][7] = bnq3.y;
    }
    __syncthreads();
    if (tid < 32) {
        float ts = 0.f, tq = 0.f;
#pragma unroll
        for (int w = 0; w < 4; w++) {
            ts += rS[w][tid >> 3][tid & 7];
            tq += rQ[w][tid >> 3][tid & 7];
        }
        atomicAdd(&sum[tid], ts);
        atomicAdd(&sq[tid], tq);
    }
}

// ---- H = affine(B) (bf16); A = H @ W2 (bf16); BN1 finalize fused -----------
__global__ void k_aff_xw(const bf16* __restrict__ B, const float* __restrict__ sum,
                         const float* __restrict__ sq, const float* __restrict__ g,
                         const float* __restrict__ be, const float* __restrict__ w,
                         bf16* __restrict__ H, bf16* __restrict__ A) {
    __shared__ float Ws[32 * 33];
    __shared__ float hs[256];
    __shared__ float sc[32], sh[32];
    int tid = threadIdx.x;
    if (tid < 32) {
        float mu = sum[tid] / (float)N_NODES;
        float var = sq[tid] / (float)N_NODES - mu * mu;
        float rs = rsqrtf(var + BN_EPS) * g[tid];
        sc[tid] = rs;
        sh[tid] = be[tid] - mu * rs;
    }
    for (int i = tid; i < 1024; i += 256)
        Ws[(i >> 5) * 33 + (i & 31)] = w[i];
    __syncthreads();
    long base = (long)blockIdx.x * 256;
    int f = tid & 31;
    float h = b2f(B[base + tid]) * sc[f] + sh[f];
    H[base + tid] = __float2bfloat16(h);
    hs[tid] = h;
    __syncthreads();
    int r = tid >> 5, hc = tid & 31;
    float acc = 0.f;
#pragma unroll
    for (int k = 0; k < 32; k++) acc += hs[r * 32 + k] * Ws[k * 33 + hc];
    A[base + tid] = __float2bfloat16(acc);
}

// ---- per-node dense stack via MFMA; BN2/fc1-const/bias finalize fused ------
#define CATP 72
#define WP1  72
#define WP2  40
#define FP1  72
#define HP   40
__global__ __launch_bounds__(256) void k_final(
    const bf16* __restrict__ Hb, const bf16* __restrict__ Bb,
    const float* __restrict__ bn2sum, const float* __restrict__ bn2sq,
    const float* __restrict__ g2, const float* __restrict__ be2,
    const float* __restrict__ xsum,
    const float* __restrict__ wih1, const float* __restrict__ wih2,
    const float* __restrict__ fw1, const float* __restrict__ fw2,
    const float* __restrict__ fb2, const float* __restrict__ fb1,
    const float* __restrict__ bih1, const float* __restrict__ bhh1,
    const float* __restrict__ bih2, const float* __restrict__ bhh2,
    float* __restrict__ out) {
    __shared__ ushort cat[128 * CATP];
    __shared__ ushort W1s[96 * WP1];
    __shared__ ushort W2s[96 * WP2];
    __shared__ ushort F1s[32 * FP1];
    __shared__ ushort h1s[128 * HP];
    __shared__ ushort h2s[128 * HP];
    __shared__ float lb1s[128], lb2s[128], fc1s[32], fw2s[32], sc2[32], sh2[32];
    int tid = threadIdx.x;
    if (tid < 128) { lb1s[tid] = bih1[tid] + bhh1[tid]; lb2s[tid] = bih2[tid] + bhh2[tid]; }
    if (tid >= 128 && tid < 160) {
        int t = tid - 128;
        float mu = bn2sum[t] / (float)N_NODES;
        float var = bn2sq[t] / (float)N_NODES - mu * mu;
        float rs = rsqrtf(var + BN_EPS) * g2[t];
        sc2[t] = rs;
        sh2[t] = be2[t] - mu * rs;
        fw2s[t] = fw2[t];
        float c = fb1[t];
        for (int f = 0; f < 32; f++)
            c += (xsum[f] / (float)N_NODES) * fw1[t * 96 + 64 + f];
        fc1s[t] = c;
    }
    for (int i = tid; i < 96 * 8; i += 256) {
        int row = i >> 3, q = i & 7;
        int c = row & 31, t = row >> 5;
        int srow = (t == 0) ? c : ((t == 1) ? 64 + c : 96 + c);
        const float* b = wih1 + srow * 64 + q * 8;
        *(uint4*)&W1s[row * WP1 + q * 8] =
            make_uint4(pk2(b), pk2(b + 2), pk2(b + 4), pk2(b + 6));
    }
    for (int i = tid; i < 96 * 4; i += 256) {
        int row = i >> 2, q = i & 3;
        int c = row & 31, t = row >> 5;
        int srow = (t == 0) ? c : ((t == 1) ? 64 + c : 96 + c);
        const float* b = wih2 + srow * 32 + q * 8;
        *(uint4*)&W2s[row * WP2 + q * 8] =
            make_uint4(pk2(b), pk2(b + 2), pk2(b + 4), pk2(b + 6));
    }
    for (int i = tid; i < 32 * 8; i += 256) {
        int row = i >> 3, q = i & 7;
        const float* b = fw1 + row * 96 + q * 8;
        *(uint4*)&F1s[row * FP1 + q * 8] =
            make_uint4(pk2(b), pk2(b + 2), pk2(b + 4), pk2(b + 6));
    }
    __syncthreads();
    {
        int ni = tid >> 1, hf = tid & 1;
        int node = blockIdx.x * 128 + ni;
        int nc = node < N_NODES ? node : N_NODES - 1;
        const uint4* src = (const uint4*)((const ushort*)(hf ? Bb : Hb) + (long)nc * 32);
        ushort* dst = &cat[ni * CATP + hf * 32];
        if (hf == 0) {
#pragma unroll
            for (int q = 0; q < 4; q++) *(uint4*)(dst + q * 8) = src[q];
        } else {
#pragma unroll
            for (int q = 0; q < 4; q++) {
                uint4 v = src[q];
                uint w[4] = {v.x, v.y, v.z, v.w};
                uint o[4];
#pragma unroll
                for (int r = 0; r < 4; r++) {
                    int e = q * 8 + r * 2;
                    o[r] = pkv(vfma(up(w[r]), (v2f){sc2[e], sc2[e + 1]},
                                    (v2f){sh2[e], sh2[e + 1]}));
                }
                *(uint4*)(dst + q * 8) = make_uint4(o[0], o[1], o[2], o[3]);
            }
        }
    }
    __syncthreads();
    int l = tid & 63, wv = tid >> 6;
    int quad = l >> 4, mr = l & 15;
    float fb2v = fb2[0];
#pragma unroll
    for (int it = 0; it < 2; it++) {
        int mt = wv * 2 + it;
        int mb = mt * 16;
        bfrag a0 = *(const bfrag*)&cat[(mb + mr) * CATP + quad * 8];
        bfrag a1 = *(const bfrag*)&cat[(mb + mr) * CATP + 32 + quad * 8];
        f32x4 g[6];
#pragma unroll
        for (int nt = 0; nt < 6; nt++) {
            bfrag b0 = *(const bfrag*)&W1s[(nt * 16 + mr) * WP1 + quad * 8];
            bfrag b1 = *(const bfrag*)&W1s[(nt * 16 + mr) * WP1 + 32 + quad * 8];
            f32x4 z = {0.f, 0.f, 0.f, 0.f};
            z = __builtin_amdgcn_mfma_f32_16x16x32_bf16(a0, b0, z, 0, 0, 0);
            z = __builtin_amdgcn_mfma_f32_16x16x32_bf16(a1, b1, z, 0, 0, 0);
            g[nt] = z;
        }
#pragma unroll
        for (int t = 0; t < 2; t++) {
            int c = t * 16 + mr;
            float bi = lb1s[c], bg = lb1s[64 + c], bo = lb1s[96 + c];
#pragma unroll
            for (int r = 0; r < 4; r++) {
                float c1 = fsig(g[t][r] + bi) * ftanh(g[2 + t][r] + bg);
                float h = fsig(g[4 + t][r] + bo) * ftanh(c1);
                bf16 hb = __float2bfloat16(h);
                h1s[(mb + quad * 4 + r) * HP + c] = *(ushort*)&hb;
            }
        }
        LDS_FENCE();
        bfrag ha = *(const bfrag*)&h1s[(mb + mr) * HP + quad * 8];
        f32x4 g2r[6];
#pragma unroll
        for (int nt = 0; nt < 6; nt++) {
            bfrag b = *(const bfrag*)&W2s[(nt * 16 + mr) * WP2 + quad * 8];
            f32x4 z = {0.f, 0.f, 0.f, 0.f};
            z = __builtin_amdgcn_mfma_f32_16x16x32_bf16(ha, b, z, 0, 0, 0);
            g2r[nt] = z;
        }
#pragma unroll
        for (int t = 0; t < 2; t++) {
            int c = t * 16 + mr;
            float bi = lb2s[c], bg = lb2s[64 + c], bo = lb2s[96 + c];
#pragma unroll
            for (int r = 0; r < 4; r++) {
                float c2 = fsig(g2r[t][r] + bi) * ftanh(g2r[2 + t][r] + bg);
                float h = fsig(g2r[4 + t][r] + bo) * ftanh(c2);
                bf16 hb = __float2bfloat16(h);
                h2s[(mb + quad * 4 + r) * HP + c] = *(ushort*)&hb;
            }
        }
        LDS_FENCE();
        bfrag hb2 = *(const bfrag*)&h2s[(mb + mr) * HP + quad * 8];
        f32x4 zt[2];
#pragma unroll
        for (int nt = 0; nt < 2; nt++) {
            bfrag f0 = *(const bfrag*)&F1s[(nt * 16 + mr) * FP1 + quad * 8];
            bfrag f1 = *(const bfrag*)&F1s[(nt * 16 + mr) * FP1 + 32 + quad * 8];
            f32x4 z = {0.f, 0.f, 0.f, 0.f};
            z = __builtin_amdgcn_mfma_f32_16x16x32_bf16(ha, f0, z, 0, 0, 0);
            z = __builtin_amdgcn_mfma_f32_16x16x32_bf16(hb2, f1, z, 0, 0, 0);
            zt[nt] = z;
        }
#pragma unroll
        for (int r = 0; r < 4; r++) {
            float s = 0.f;
#pragma unroll
            for (int t = 0; t < 2; t++) {
                int j = t * 16 + mr;
                s += fmaxf(zt[t][r] + fc1s[j], 0.f) * fw2s[j];
            }
            s += __shfl_xor(s, 1); s += __shfl_xor(s, 2);
            s += __shfl_xor(s, 4); s += __shfl_xor(s, 8);
            int node = blockIdx.x * 128 + mb + quad * 4 + r;
            if (mr == 0 && node < N_NODES) out[node] = s + fb2v;
        }
    }
}

extern "C" void kernel_launch(void* const* d_in, const int* in_sizes, int n_in,
                              void* d_out, int out_size, void* d_ws, size_t ws_size,
                              hipStream_t stream) {
    const float* x    = (const float*)d_in[0];
    const int*   ei   = (const int*)d_in[1];
    const float* ew   = (const float*)d_in[2];
    const float* w1   = (const float*)d_in[3];
    const float* b1   = (const float*)d_in[4];
    const float* g1   = (const float*)d_in[5];
    const float* be1  = (const float*)d_in[6];
    const float* w2   = (const float*)d_in[7];
    const float* b2   = (const float*)d_in[8];
    const float* g2   = (const float*)d_in[9];
    const float* be2  = (const float*)d_in[10];
    const float* wih1 = (const float*)d_in[11];
    const float* bih1 = (const float*)d_in[13];
    const float* bhh1 = (const float*)d_in[14];
    const float* wih2 = (const float*)d_in[15];
    const float* bih2 = (const float*)d_in[17];
    const float* bhh2 = (const float*)d_in[18];
    const float* fw1  = (const float*)d_in[19];
    const float* fb1  = (const float*)d_in[20];
    const float* fw2  = (const float*)d_in[21];
    const float* fb2  = (const float*)d_in[22];
    float* out = (float*)d_out;

    // ---- workspace layout (36.1 MB; ws >= 40.5 MB proven) ------------------
    // cse dead after k_fine; H/B overlay its 12.8 MB region.
    char* ws = (char*)d_ws;
    float* stats = (float*)ws;                          // 160 floats used
    float* xsum   = stats + 0;
    float* bn1sum = stats + 32;
    float* bn1sq  = stats + 64;
    float* bn2sum = stats + 96;
    float* bn2sq  = stats + 128;
    int*   tot   = (int*)  (ws + 4096);                 // 392 i
    int*   cbase = (int*)  (ws + 8192);                 // 392 i
    int*   ghist = (int*)  (ws + 16384);                // 391*782 i -> 1,239,432
    int*   off   = (int*)  (ws + 1310720);              // 100001 i -> 1,710,724
    float* dinv  = (float*)(ws + 1835008);              // 100000 f -> 2,235,008
    int2*  epk   = (int2*) (ws + 2621440);              // 1.6M int2 -> 15,421,440
    int2*  cse   = (int2*) (ws + 16777216);             // 1.6M int2 -> 29,577,216
    bf16*  H     = (bf16*) (ws + 16777216);             // overlay (6.4MB)
    bf16*  B     = (bf16*) (ws + 23177216);             // overlay (6.4MB)
    bf16*  A     = (bf16*) (ws + 29622272);             // 6.4MB -> 36,022,272

    if (ws_size < 40497152ull) {
        k_marker<<<(N_NODES + 255) / 256, 256, 0, stream>>>(out, N_NODES, 911.f);
        return;
    }

    k_zero_s<<<1, 256, 0, stream>>>(stats);
    k_count<<<NBLK, 256, 0, stream>>>(ei, x, w1, ghist, A);
    k_tot<<<NCB, 256, 0, stream>>>(ghist, tot, x, xsum);
    k_base<<<1, 256, 0, stream>>>(tot, cbase);
    k_rowscan<<<NCB, 256, 0, stream>>>(ghist, cbase);
    k_cscatter<<<NBLK, 256, 0, stream>>>(ei, ew, ghist, cse);
    k_fine<<<NCB, 256, 0, stream>>>(cse, cbase, epk, off, dinv);
    k_norm<<<6250, 256, 0, stream>>>(epk, dinv);
    k_gcn<<<1563, 256, 0, stream>>>(off, epk, A, dinv, b1, B, bn1sum, bn1sq);
    k_aff_xw<<<12500, 256, 0, stream>>>(B, bn1sum, bn1sq, g1, be1, w2, H, A);
    k_gcn<<<1563, 256, 0, stream>>>(off, epk, A, dinv, b2, B, bn2sum, bn2sq);
    k_final<<<782, 256, 0, stream>>>(H, B, bn2sum, bn2sq, g2, be2, xsum,
                                     wih1, wih2, fw1, fw2, fb2, fb1,
                                     bih1, bhh1, bih2, bhh2, out);
}

// Round 4
// 310.178 us; speedup vs baseline: 1.4437x; 1.0576x over previous
//
#include <hip/hip_runtime.h>
#include <hip/hip_bf16.h>

#define N_NODES 100000
#define N_EDGES 1600000
#define BN_EPS 1e-5f
#define NCB  391    // coarse buckets = ceil(100000/256), bucket = dst>>8
#define NBLK 782    // edge blocks, 2048 edges each (782*2048 >= 1.6M)
#define EPB  2048
#define CAP  4608   // LDS staging capacity per fine bucket (avg 4092, ~8 sigma)

typedef __hip_bfloat16 bf16;
typedef unsigned long long ull;
typedef float v2f __attribute__((ext_vector_type(2)));
typedef short bfrag __attribute__((ext_vector_type(8)));   // 8 bf16 = 4 VGPRs
typedef float f32x4 __attribute__((ext_vector_type(4)));

__device__ __forceinline__ float b2f(bf16 v) { return __bfloat162float(v); }
__device__ __forceinline__ float frcp(float x) { return __builtin_amdgcn_rcpf(x); }
__device__ __forceinline__ float fsig(float x) { return frcp(1.0f + __expf(-x)); }
__device__ __forceinline__ float ftanh(float x) {
    return 1.0f - 2.0f * frcp(__expf(2.0f * x) + 1.0f);
}
__device__ __forceinline__ v2f up(uint u) {
    return (v2f){__uint_as_float(u << 16), __uint_as_float(u & 0xffff0000u)};
}
__device__ __forceinline__ v2f vfma(v2f a, v2f b, v2f c) {
    return __builtin_elementwise_fma(a, b, c);
}
__device__ __forceinline__ uint pk2(const float* p) {
    bf16 a = __float2bfloat16(p[0]), b = __float2bfloat16(p[1]);
    return (uint)*(ushort*)&a | ((uint)*(ushort*)&b << 16);
}
__device__ __forceinline__ uint pkv(v2f v) {
    bf16 a = __float2bfloat16(v.x), b = __float2bfloat16(v.y);
    return (uint)*(ushort*)&a | ((uint)*(ushort*)&b << 16);
}
#define LDS_FENCE() __asm__ volatile("s_waitcnt lgkmcnt(0)" ::: "memory")

// block-wide (256 thr) exclusive scan; wsum = LDS int[4]; total broadcast
__device__ __forceinline__ int blk_exscan(int v, int tid, int* wsum, int* total) {
    int lane = tid & 63, w = tid >> 6;
    int s = v;
    for (int d = 1; d < 64; d <<= 1) {
        int u = __shfl_up(s, d, 64);
        if (lane >= d) s += u;
    }
    if (lane == 63) wsum[w] = s;
    __syncthreads();
    int wb = 0;
    for (int i = 0; i < w; i++) wb += wsum[i];
    int tot = wsum[0] + wsum[1] + wsum[2] + wsum[3];
    __syncthreads();            // wsum reusable by next call
    *total = tot;
    return wb + s - v;
}

// ---- utility ---------------------------------------------------------------
__global__ void k_marker(float* __restrict__ p, int n, float v) {
    int i = blockIdx.x * 256 + threadIdx.x;
    if (i < n) p[i] = v;
}

// ---- P1: per-block coarse histogram (LDS atomics only) + A = x @ W1 --------
// block 0 additionally zeroes the stats scratch (consumed by later kernels).
__global__ __launch_bounds__(256) void k_count(
    const int* __restrict__ ei, const float* __restrict__ x,
    const float* __restrict__ w1, int* __restrict__ ghist,
    bf16* __restrict__ A, float* __restrict__ stats) {
    __shared__ int hist[NCB];
    __shared__ float Ws[32 * 33];
    __shared__ float xs[512];
    int tid = threadIdx.x, blk = blockIdx.x;
    if (blk == 0 && tid < 192) stats[tid] = 0.f;
    for (int i = tid; i < NCB; i += 256) hist[i] = 0;
    for (int i = tid; i < 1024; i += 256)
        Ws[(i >> 5) * 33 + (i & 31)] = w1[i];
    __syncthreads();
#pragma unroll
    for (int k = 0; k < 8; k++) {
        int e = blk * EPB + k * 256 + tid;
        if (e < N_EDGES) atomicAdd(&hist[ei[N_EDGES + e] >> 8], 1);
    }
    // xw1: this block covers 4096 x-elems (782*4096 = 3,203,072 > 3.2M: guard)
    for (int g = 0; g < 8; g++) {
        long base = (long)blk * 4096 + g * 512;
        xs[tid] = (base + tid < (long)N_NODES * 32) ? x[base + tid] : 0.f;
        xs[256 + tid] = (base + 256 + tid < (long)N_NODES * 32) ? x[base + 256 + tid] : 0.f;
        __syncthreads();
        int r = tid >> 5, h = tid & 31;
        float acc0 = 0.f, acc1 = 0.f;
#pragma unroll
        for (int f = 0; f < 32; f++) {
            float wv = Ws[f * 33 + h];
            acc0 += xs[r * 32 + f] * wv;
            acc1 += xs[256 + r * 32 + f] * wv;
        }
        if (base + tid < (long)N_NODES * 32) A[base + tid] = __float2bfloat16(acc0);
        if (base + 256 + tid < (long)N_NODES * 32) A[base + 256 + tid] = __float2bfloat16(acc1);
        __syncthreads();
    }
    for (int i = tid; i < NCB; i += 256) ghist[(long)i * NBLK + blk] = hist[i];
}

// ---- P2a: bucket totals (row sums) + column sums of x (skip_avg) -----------
__global__ void k_tot(const int* __restrict__ ghist, int* __restrict__ tot,
                      const float* __restrict__ x, float* __restrict__ xsum) {
    __shared__ int sc[256];
    __shared__ float sf[256];
    int tid = threadIdx.x, b = blockIdx.x;
    const int* row = ghist + (long)b * NBLK;
    int acc = 0;
    for (int i = tid; i < NBLK; i += 256) acc += row[i];
    sc[tid] = acc;
    int f = tid & 31, rg = tid >> 5;
    float accf = 0.f;
    for (int n = b * 8 + rg; n < N_NODES; n += NCB * 8)
        accf += x[n * 32 + f];
    sf[tid] = accf;
    __syncthreads();
    for (int st = 128; st >= 1; st >>= 1) {
        if (tid < st) {
            sc[tid] += sc[tid + st];
            if (st >= 32) sf[tid] += sf[tid + st];
        }
        __syncthreads();
    }
    if (tid == 0) tot[b] = sc[0];
    if (tid < 32) atomicAdd(&xsum[tid], sf[tid]);
}

// ---- P2b: per-bucket row scan (computes own global base from tot) ----------
// Also publishes cbase[b] (and cbase[NCB]) for k_fine; k_base launch removed.
__global__ void k_rowscan(int* __restrict__ ghist, const int* __restrict__ tot,
                          int* __restrict__ cbase) {
    __shared__ int redS[256];
    __shared__ int wsum[4];
    __shared__ int carry;
    int tid = threadIdx.x, b = blockIdx.x;
    int accb = 0;
    for (int i = tid; i < NCB; i += 256)
        if (i < b) accb += tot[i];
    redS[tid] = accb; __syncthreads();
    for (int st = 128; st >= 1; st >>= 1) {
        if (tid < st) redS[tid] += redS[tid + st];
        __syncthreads();
    }
    int base = redS[0];
    if (tid == 0) {
        cbase[b] = base;
        if (b == NCB - 1) cbase[NCB] = base + tot[b];
        carry = 0;
    }
    __syncthreads();
    int* row = ghist + (long)b * NBLK;
    for (int r = 0; r < 4; r++) {
        int idx = r * 256 + tid;
        int v = (idx < NBLK) ? row[idx] : 0;
        int T;
        int ex = blk_exscan(v, tid, wsum, &T);
        int c = carry;
        if (idx < NBLK) row[idx] = base + c + ex;
        __syncthreads();
        if (tid == 0) carry = c + T;
        __syncthreads();
    }
}

// ---- P3: coarse scatter into bucket segments (no global atomics) -----------
// cse[pos] = { src | dlow<<17 , ew }  (src < 2^17, dlow 8 bits)
__global__ __launch_bounds__(256) void k_cscatter(
    const int* __restrict__ ei, const float* __restrict__ ew,
    const int* __restrict__ gbase, int2* __restrict__ cse) {
    __shared__ int cnt[NCB];
    __shared__ int cur[NCB];
    int tid = threadIdx.x, blk = blockIdx.x;
    for (int i = tid; i < NCB; i += 256) {
        cnt[i] = 0;
        cur[i] = gbase[(long)i * NBLK + blk];
    }
    __syncthreads();
#pragma unroll
    for (int k = 0; k < 8; k++) {
        int e = blk * EPB + k * 256 + tid;
        if (e < N_EDGES) {
            int d = ei[N_EDGES + e];
            int b = d >> 8;
            int r = atomicAdd(&cnt[b], 1);
            cse[cur[b] + r] = make_int2(ei[e] | ((d & 255) << 17),
                                        __float_as_int(ew[e]));
        }
    }
}

// ---- P4: fine pass per bucket: counts, deg->dinv, off, coalesced epk -------
// epk[slot] = { src, ew * dinv[dst] }   (dinv[src] applied in P5)
__global__ __launch_bounds__(256) void k_fine(
    const int2* __restrict__ cse, const int* __restrict__ cbase,
    int2* __restrict__ epk, int* __restrict__ off, float* __restrict__ dinv) {
    __shared__ int2 outL[CAP];
    __shared__ int cnt[256];
    __shared__ float degw[256];
    __shared__ int cur[256];
    __shared__ int wsum[4];
    int tid = threadIdx.x, b = blockIdx.x;
    int s0 = cbase[b], s1 = cbase[b + 1];
    int segn = s1 - s0;
    cnt[tid] = 0;
    degw[tid] = 0.f;
    __syncthreads();
    for (int p = s0 + tid; p < s1; p += 256) {
        int2 v = cse[p];
        int dl = (v.x >> 17) & 255;
        atomicAdd(&cnt[dl], 1);
        atomicAdd(&degw[dl], __int_as_float(v.y));
    }
    __syncthreads();
    int T;
    int lofs = blk_exscan(cnt[tid], tid, wsum, &T);
    int nn = min(256, N_NODES - b * 256);
    float dv = rsqrtf(degw[tid] + 1.0f);
    if (tid < nn) {
        dinv[b * 256 + tid] = dv;
        off[b * 256 + tid] = s0 + lofs;
    }
    if (b == 0 && tid == 0) off[N_NODES] = N_EDGES;
    cur[tid] = lofs;
    __syncthreads();
    degw[tid] = dv;               // reuse as dinv[dlow] table
    __syncthreads();
    bool staged = segn <= CAP;
    for (int p = s0 + tid; p < s1; p += 256) {
        int2 v = cse[p];
        int dl = (v.x >> 17) & 255;
        int slot = atomicAdd(&cur[dl], 1);
        int2 o = make_int2(v.x & 0x1FFFF,
                           __float_as_int(__int_as_float(v.y) * degw[dl]));
        if (staged) outL[slot] = o;
        else epk[s0 + slot] = o;
    }
    __syncthreads();
    if (staged)
        for (int p = tid; p < segn; p += 256) epk[s0 + p] = outL[p];
}

// ---- P5: epk.y *= dinv[src] (sequential rw, L2-resident gather) ------------
__global__ void k_norm(int2* __restrict__ epk, const float* __restrict__ dinv) {
    int e = blockIdx.x * 256 + threadIdx.x;
    int2 v = epk[e];
    epk[e] = make_int2(v.x, __float_as_int(__int_as_float(v.y) * dinv[v.x]));
}

// ---- pull-mode GCN: 4 lanes/node, uint4 (8-feature) gathers, 8-edge batch --
// A wave covers 16 nodes; each of the 8 batched gather instructions has 16
// distinct 64B lines in flight -> 128 lines/wave outstanding. Tail edges
// folded via clamped index + zeroed norm.
__global__ __launch_bounds__(256) void k_gcn(
    const int* __restrict__ off, const int2* __restrict__ epk,
    const bf16* __restrict__ A, const float* __restrict__ dinv,
    const float* __restrict__ bias, bf16* __restrict__ B,
    float* __restrict__ sum, float* __restrict__ sq) {
    __shared__ float rS[4][4][8];
    __shared__ float rQ[4][4][8];
    const uint4* A4 = (const uint4*)A;
    uint4* B4 = (uint4*)B;
    int tid = threadIdx.x, fp = tid & 3, q = tid >> 2;
    int n = blockIdx.x * 64 + q;
    bool valid = n < N_NODES;

    v2f bv0 = (v2f){bias[8 * fp + 0], bias[8 * fp + 1]};
    v2f bv1 = (v2f){bias[8 * fp + 2], bias[8 * fp + 3]};
    v2f bv2 = (v2f){bias[8 * fp + 4], bias[8 * fp + 5]};
    v2f bv3 = (v2f){bias[8 * fp + 6], bias[8 * fp + 7]};

    v2f aA0 = (v2f)0.f, aA1 = (v2f)0.f, aA2 = (v2f)0.f, aA3 = (v2f)0.f;
    v2f aB0 = (v2f)0.f, aB1 = (v2f)0.f, aB2 = (v2f)0.f, aB3 = (v2f)0.f;

    int lo = 0, hi = 0;
    if (valid) { lo = off[n]; hi = off[n + 1]; }

    for (int p = lo; p < hi; p += 8) {
        int q1 = min(p + 1, hi - 1), q2 = min(p + 2, hi - 1);
        int q3 = min(p + 3, hi - 1), q4 = min(p + 4, hi - 1);
        int q5 = min(p + 5, hi - 1), q6 = min(p + 6, hi - 1);
        int q7 = min(p + 7, hi - 1);
        int2 e0 = epk[p],  e1 = epk[q1], e2 = epk[q2], e3 = epk[q3];
        int2 e4 = epk[q4], e5 = epk[q5], e6 = epk[q6], e7 = epk[q7];
        uint4 g0 = A4[(long)e0.x * 4 + fp];
        uint4 g1 = A4[(long)e1.x * 4 + fp];
        uint4 g2 = A4[(long)e2.x * 4 + fp];
        uint4 g3 = A4[(long)e3.x * 4 + fp];
        uint4 g4 = A4[(long)e4.x * 4 + fp];
        uint4 g5 = A4[(long)e5.x * 4 + fp];
        uint4 g6 = A4[(long)e6.x * 4 + fp];
        uint4 g7 = A4[(long)e7.x * 4 + fp];
        float n0 = __int_as_float(e0.y);
        float n1 = (p + 1 < hi) ? __int_as_float(e1.y) : 0.f;
        float n2 = (p + 2 < hi) ? __int_as_float(e2.y) : 0.f;
        float n3 = (p + 3 < hi) ? __int_as_float(e3.y) : 0.f;
        float n4 = (p + 4 < hi) ? __int_as_float(e4.y) : 0.f;
        float n5 = (p + 5 < hi) ? __int_as_float(e5.y) : 0.f;
        float n6 = (p + 6 < hi) ? __int_as_float(e6.y) : 0.f;
        float n7 = (p + 7 < hi) ? __int_as_float(e7.y) : 0.f;
        v2f v0 = (v2f){n0, n0}, v1 = (v2f){n1, n1};
        v2f v2 = (v2f){n2, n2}, v3 = (v2f){n3, n3};
        v2f v4 = (v2f){n4, n4}, v5 = (v2f){n5, n5};
        v2f v6 = (v2f){n6, n6}, v7 = (v2f){n7, n7};
        aA0 = vfma(up(g0.x), v0, aA0); aA1 = vfma(up(g0.y), v0, aA1);
        aA2 = vfma(up(g0.z), v0, aA2); aA3 = vfma(up(g0.w), v0, aA3);
        aB0 = vfma(up(g1.x), v1, aB0); aB1 = vfma(up(g1.y), v1, aB1);
        aB2 = vfma(up(g1.z), v1, aB2); aB3 = vfma(up(g1.w), v1, aB3);
        aA0 = vfma(up(g2.x), v2, aA0); aA1 = vfma(up(g2.y), v2, aA1);
        aA2 = vfma(up(g2.z), v2, aA2); aA3 = vfma(up(g2.w), v2, aA3);
        aB0 = vfma(up(g3.x), v3, aB0); aB1 = vfma(up(g3.y), v3, aB1);
        aB2 = vfma(up(g3.z), v3, aB2); aB3 = vfma(up(g3.w), v3, aB3);
        aA0 = vfma(up(g4.x), v4, aA0); aA1 = vfma(up(g4.y), v4, aA1);
        aA2 = vfma(up(g4.z), v4, aA2); aA3 = vfma(up(g4.w), v4, aA3);
        aB0 = vfma(up(g5.x), v5, aB0); aB1 = vfma(up(g5.y), v5, aB1);
        aB2 = vfma(up(g5.z), v5, aB2); aB3 = vfma(up(g5.w), v5, aB3);
        aA0 = vfma(up(g6.x), v6, aA0); aA1 = vfma(up(g6.y), v6, aA1);
        aA2 = vfma(up(g6.z), v6, aA2); aA3 = vfma(up(g6.w), v6, aA3);
        aB0 = vfma(up(g7.x), v7, aB0); aB1 = vfma(up(g7.y), v7, aB1);
        aB2 = vfma(up(g7.z), v7, aB2); aB3 = vfma(up(g7.w), v7, aB3);
    }

    v2f bns0 = (v2f)0.f, bns1 = (v2f)0.f, bns2 = (v2f)0.f, bns3 = (v2f)0.f;
    v2f bnq0 = (v2f)0.f, bnq1 = (v2f)0.f, bnq2 = (v2f)0.f, bnq3 = (v2f)0.f;

    if (valid) {
        float dv = dinv[n];
        float si = dv * dv;                      // 1/(deg+1)
        v2f sv = (v2f){si, si};
        uint4 qs = A4[(long)n * 4 + fp];
        v2f o0 = vfma(up(qs.x), sv, aA0 + aB0) + bv0;
        v2f o1 = vfma(up(qs.y), sv, aA1 + aB1) + bv1;
        v2f o2 = vfma(up(qs.z), sv, aA2 + aB2) + bv2;
        v2f o3 = vfma(up(qs.w), sv, aA3 + aB3) + bv3;
        o0.x = fmaxf(o0.x, 0.f); o0.y = fmaxf(o0.y, 0.f);
        o1.x = fmaxf(o1.x, 0.f); o1.y = fmaxf(o1.y, 0.f);
        o2.x = fmaxf(o2.x, 0.f); o2.y = fmaxf(o2.y, 0.f);
        o3.x = fmaxf(o3.x, 0.f); o3.y = fmaxf(o3.y, 0.f);
        uint4 ov = make_uint4(pkv(o0), pkv(o1), pkv(o2), pkv(o3));
        B4[(long)n * 4 + fp] = ov;
        bns0 = o0; bns1 = o1; bns2 = o2; bns3 = o3;
        bnq0 = o0 * o0; bnq1 = o1 * o1; bnq2 = o2 * o2; bnq3 = o3 * o3;
    }

#pragma unroll
    for (int st = 4; st <= 32; st <<= 1) {
        bns0.x += __shfl_xor(bns0.x, st); bns0.y += __shfl_xor(bns0.y, st);
        bns1.x += __shfl_xor(bns1.x, st); bns1.y += __shfl_xor(bns1.y, st);
        bns2.x += __shfl_xor(bns2.x, st); bns2.y += __shfl_xor(bns2.y, st);
        bns3.x += __shfl_xor(bns3.x, st); bns3.y += __shfl_xor(bns3.y, st);
        bnq0.x += __shfl_xor(bnq0.x, st); bnq0.y += __shfl_xor(bnq0.y, st);
        bnq1.x += __shfl_xor(bnq1.x, st); bnq1.y += __shfl_xor(bnq1.y, st);
        bnq2.x += __shfl_xor(bnq2.x, st); bnq2.y += __shfl_xor(bnq2.y, st);
        bnq3.x += __shfl_xor(bnq3.x, st); bnq3.y += __shfl_xor(bnq3.y, st);
    }
    int lane = tid & 63, wv = tid >> 6;
    if (lane < 4) {
        rS[wv][lane][0] = bns0.x; rS[wv][lane][1] = bns0.y;
        rS[wv][lane][2] = bns1.x; rS[wv][lane][3] = bns1.y;
        rS[wv][lane][4] = bns2.x; rS[wv][lane][5] = bns2.y;
        rS[wv][lane][6] = bns3.x; rS[wv][lane][7] = bns3.y;
        rQ[wv][lane][0] = bnq0.x; rQ[wv][lane][1] = bnq0.y;
        rQ[wv][lane][2] = bnq1.x; rQ[wv][lane][3] = bnq1.y;
        rQ[wv][lane][4] = bnq2.x; rQ[wv][lane][5] = bnq2.y;
        rQ[wv][lane][6] = bnq3.x; rQ[wv][lane][7] = bnq3.y;
    }
    __syncthreads();
    if (tid < 32) {
        float ts = 0.f, tq = 0.f;
#pragma unroll
        for (int w = 0; w < 4; w++) {
            ts += rS[w][tid >> 3][tid & 7];
            tq += rQ[w][tid >> 3][tid & 7];
        }
        atomicAdd(&sum[tid], ts);
        atomicAdd(&sq[tid], tq);
    }
}

// ---- H = affine(B) (bf16); A = H @ W2 (bf16); BN1 finalize fused -----------
__global__ void k_aff_xw(const bf16* __restrict__ B, const float* __restrict__ sum,
                         const float* __restrict__ sq, const float* __restrict__ g,
                         const float* __restrict__ be, const float* __restrict__ w,
                         bf16* __restrict__ H, bf16* __restrict__ A) {
    __shared__ float Ws[32 * 33];
    __shared__ float hs[256];
    __shared__ float sc[32], sh[32];
    int tid = threadIdx.x;
    if (tid < 32) {
        float mu = sum[tid] / (float)N_NODES;
        float var = sq[tid] / (float)N_NODES - mu * mu;
        float rs = rsqrtf(var + BN_EPS) * g[tid];
        sc[tid] = rs;
        sh[tid] = be[tid] - mu * rs;
    }
    for (int i = tid; i < 1024; i += 256)
        Ws[(i >> 5) * 33 + (i & 31)] = w[i];
    __syncthreads();
    long base = (long)blockIdx.x * 256;
    int f = tid & 31;
    float h = b2f(B[base + tid]) * sc[f] + sh[f];
    H[base + tid] = __float2bfloat16(h);
    hs[tid] = h;
    __syncthreads();
    int r = tid >> 5, hc = tid & 31;
    float acc = 0.f;
#pragma unroll
    for (int k = 0; k < 32; k++) acc += hs[r * 32 + k] * Ws[k * 33 + hc];
    A[base + tid] = __float2bfloat16(acc);
}

// ---- per-node dense stack via MFMA; BN2/fc1-const/bias finalize fused ------
#define CATP 72
#define WP1  72
#define WP2  40
#define FP1  72
#define HP   40
__global__ __launch_bounds__(256) void k_final(
    const bf16* __restrict__ Hb, const bf16* __restrict__ Bb,
    const float* __restrict__ bn2sum, const float* __restrict__ bn2sq,
    const float* __restrict__ g2, const float* __restrict__ be2,
    const float* __restrict__ xsum,
    const float* __restrict__ wih1, const float* __restrict__ wih2,
    const float* __restrict__ fw1, const float* __restrict__ fw2,
    const float* __restrict__ fb2, const float* __restrict__ fb1,
    const float* __restrict__ bih1, const float* __restrict__ bhh1,
    const float* __restrict__ bih2, const float* __restrict__ bhh2,
    float* __restrict__ out) {
    __shared__ ushort cat[128 * CATP];
    __shared__ ushort W1s[96 * WP1];
    __shared__ ushort W2s[96 * WP2];
    __shared__ ushort F1s[32 * FP1];
    __shared__ ushort h1s[128 * HP];
    __shared__ ushort h2s[128 * HP];
    __shared__ float lb1s[128], lb2s[128], fc1s[32], fw2s[32], sc2[32], sh2[32];
    int tid = threadIdx.x;
    if (tid < 128) { lb1s[tid] = bih1[tid] + bhh1[tid]; lb2s[tid] = bih2[tid] + bhh2[tid]; }
    if (tid >= 128 && tid < 160) {
        int t = tid - 128;
        float mu = bn2sum[t] / (float)N_NODES;
        float var = bn2sq[t] / (float)N_NODES - mu * mu;
        float rs = rsqrtf(var + BN_EPS) * g2[t];
        sc2[t] = rs;
        sh2[t] = be2[t] - mu * rs;
        fw2s[t] = fw2[t];
        float c = fb1[t];
        for (int f = 0; f < 32; f++)
            c += (xsum[f] / (float)N_NODES) * fw1[t * 96 + 64 + f];
        fc1s[t] = c;
    }
    for (int i = tid; i < 96 * 8; i += 256) {
        int row = i >> 3, q = i & 7;
        int c = row & 31, t = row >> 5;
        int srow = (t == 0) ? c : ((t == 1) ? 64 + c : 96 + c);
        const float* b = wih1 + srow * 64 + q * 8;
        *(uint4*)&W1s[row * WP1 + q * 8] =
            make_uint4(pk2(b), pk2(b + 2), pk2(b + 4), pk2(b + 6));
    }
    for (int i = tid; i < 96 * 4; i += 256) {
        int row = i >> 2, q = i & 3;
        int c = row & 31, t = row >> 5;
        int srow = (t == 0) ? c : ((t == 1) ? 64 + c : 96 + c);
        const float* b = wih2 + srow * 32 + q * 8;
        *(uint4*)&W2s[row * WP2 + q * 8] =
            make_uint4(pk2(b), pk2(b + 2), pk2(b + 4), pk2(b + 6));
    }
    for (int i = tid; i < 32 * 8; i += 256) {
        int row = i >> 3, q = i & 7;
        const float* b = fw1 + row * 96 + q * 8;
        *(uint4*)&F1s[row * FP1 + q * 8] =
            make_uint4(pk2(b), pk2(b + 2), pk2(b + 4), pk2(b + 6));
    }
    __syncthreads();
    {
        int ni = tid >> 1, hf = tid & 1;
        int node = blockIdx.x * 128 + ni;
        int nc = node < N_NODES ? node : N_NODES - 1;
        const uint4* src = (const uint4*)((const ushort*)(hf ? Bb : Hb) + (long)nc * 32);
        ushort* dst = &cat[ni * CATP + hf * 32];
        if (hf == 0) {
#pragma unroll
            for (int q = 0; q < 4; q++) *(uint4*)(dst + q * 8) = src[q];
        } else {
#pragma unroll
            for (int q = 0; q < 4; q++) {
                uint4 v = src[q];
                uint w[4] = {v.x, v.y, v.z, v.w};
                uint o[4];
#pragma unroll
                for (int r = 0; r < 4; r++) {
                    int e = q * 8 + r * 2;
                    o[r] = pkv(vfma(up(w[r]), (v2f){sc2[e], sc2[e + 1]},
                                    (v2f){sh2[e], sh2[e + 1]}));
                }
                *(uint4*)(dst + q * 8) = make_uint4(o[0], o[1], o[2], o[3]);
            }
        }
    }
    __syncthreads();
    int l = tid & 63, wv = tid >> 6;
    int quad = l >> 4, mr = l & 15;
    float fb2v = fb2[0];
#pragma unroll
    for (int it = 0; it < 2; it++) {
        int mt = wv * 2 + it;
        int mb = mt * 16;
        bfrag a0 = *(const bfrag*)&cat[(mb + mr) * CATP + quad * 8];
        bfrag a1 = *(const bfrag*)&cat[(mb + mr) * CATP + 32 + quad * 8];
        f32x4 g[6];
#pragma unroll
        for (int nt = 0; nt < 6; nt++) {
            bfrag b0 = *(const bfrag*)&W1s[(nt * 16 + mr) * WP1 + quad * 8];
            bfrag b1 = *(const bfrag*)&W1s[(nt * 16 + mr) * WP1 + 32 + quad * 8];
            f32x4 z = {0.f, 0.f, 0.f, 0.f};
            z = __builtin_amdgcn_mfma_f32_16x16x32_bf16(a0, b0, z, 0, 0, 0);
            z = __builtin_amdgcn_mfma_f32_16x16x32_bf16(a1, b1, z, 0, 0, 0);
            g[nt] = z;
        }
#pragma unroll
        for (int t = 0; t < 2; t++) {
            int c = t * 16 + mr;
            float bi = lb1s[c], bg = lb1s[64 + c], bo = lb1s[96 + c];
#pragma unroll
            for (int r = 0; r < 4; r++) {
                float c1 = fsig(g[t][r] + bi) * ftanh(g[2 + t][r] + bg);
                float h = fsig(g[4 + t][r] + bo) * ftanh(c1);
                bf16 hb = __float2bfloat16(h);
                h1s[(mb + quad * 4 + r) * HP + c] = *(ushort*)&hb;
            }
        }
        LDS_FENCE();
        bfrag ha = *(const bfrag*)&h1s[(mb + mr) * HP + quad * 8];
        f32x4 g2r[6];
#pragma unroll
        for (int nt = 0; nt < 6; nt++) {
            bfrag b = *(const bfrag*)&W2s[(nt * 16 + mr) * WP2 + quad * 8];
            f32x4 z = {0.f, 0.f, 0.f, 0.f};
            z = __builtin_amdgcn_mfma_f32_16x16x32_bf16(ha, b, z, 0, 0, 0);
            g2r[nt] = z;
        }
#pragma unroll
        for (int t = 0; t < 2; t++) {
            int c = t * 16 + mr;
            float bi = lb2s[c], bg = lb2s[64 + c], bo = lb2s[96 + c];
#pragma unroll
            for (int r = 0; r < 4; r++) {
                float c2 = fsig(g2r[t][r] + bi) * ftanh(g2r[2 + t][r] + bg);
                float h = fsig(g2r[4 + t][r] + bo) * ftanh(c2);
                bf16 hb = __float2bfloat16(h);
                h2s[(mb + quad * 4 + r) * HP + c] = *(ushort*)&hb;
            }
        }
        LDS_FENCE();
        bfrag hb2 = *(const bfrag*)&h2s[(mb + mr) * HP + quad * 8];
        f32x4 zt[2];
#pragma unroll
        for (int nt = 0; nt < 2; nt++) {
            bfrag f0 = *(const bfrag*)&F1s[(nt * 16 + mr) * FP1 + quad * 8];
            bfrag f1 = *(const bfrag*)&F1s[(nt * 16 + mr) * FP1 + 32 + quad * 8];
            f32x4 z = {0.f, 0.f, 0.f, 0.f};
            z = __builtin_amdgcn_mfma_f32_16x16x32_bf16(ha, f0, z, 0, 0, 0);
            z = __builtin_amdgcn_mfma_f32_16x16x32_bf16(hb2, f1, z, 0, 0, 0);
            zt[nt] = z;
        }
#pragma unroll
        for (int r = 0; r < 4; r++) {
            float s = 0.f;
#pragma unroll
            for (int t = 0; t < 2; t++) {
                int j = t * 16 + mr;
                s += fmaxf(zt[t][r] + fc1s[j], 0.f) * fw2s[j];
            }
            s += __shfl_xor(s, 1); s += __shfl_xor(s, 2);
            s += __shfl_xor(s, 4); s += __shfl_xor(s, 8);
            int node = blockIdx.x * 128 + mb + quad * 4 + r;
            if (mr == 0 && node < N_NODES) out[node] = s + fb2v;
        }
    }
}

extern "C" void kernel_launch(void* const* d_in, const int* in_sizes, int n_in,
                              void* d_out, int out_size, void* d_ws, size_t ws_size,
                              hipStream_t stream) {
    const float* x    = (const float*)d_in[0];
    const int*   ei   = (const int*)d_in[1];
    const float* ew   = (const float*)d_in[2];
    const float* w1   = (const float*)d_in[3];
    const float* b1   = (const float*)d_in[4];
    const float* g1   = (const float*)d_in[5];
    const float* be1  = (const float*)d_in[6];
    const float* w2   = (const float*)d_in[7];
    const float* b2   = (const float*)d_in[8];
    const float* g2   = (const float*)d_in[9];
    const float* be2  = (const float*)d_in[10];
    const float* wih1 = (const float*)d_in[11];
    const float* bih1 = (const float*)d_in[13];
    const float* bhh1 = (const float*)d_in[14];
    const float* wih2 = (const float*)d_in[15];
    const float* bih2 = (const float*)d_in[17];
    const float* bhh2 = (const float*)d_in[18];
    const float* fw1  = (const float*)d_in[19];
    const float* fb1  = (const float*)d_in[20];
    const float* fw2  = (const float*)d_in[21];
    const float* fb2  = (const float*)d_in[22];
    float* out = (float*)d_out;

    // ---- workspace layout (36.1 MB; ws >= 40.5 MB proven) ------------------
    // cse dead after k_fine; H/B overlay its 12.8 MB region.
    char* ws = (char*)d_ws;
    float* stats = (float*)ws;                          // 160 floats used
    float* xsum   = stats + 0;
    float* bn1sum = stats + 32;
    float* bn1sq  = stats + 64;
    float* bn2sum = stats + 96;
    float* bn2sq  = stats + 128;
    int*   tot   = (int*)  (ws + 4096);                 // 392 i
    int*   cbase = (int*)  (ws + 8192);                 // 392 i
    int*   ghist = (int*)  (ws + 16384);                // 391*782 i -> 1,239,432
    int*   off   = (int*)  (ws + 1310720);              // 100001 i -> 1,710,724
    float* dinv  = (float*)(ws + 1835008);              // 100000 f -> 2,235,008
    int2*  epk   = (int2*) (ws + 2621440);              // 1.6M int2 -> 15,421,440
    int2*  cse   = (int2*) (ws + 16777216);             // 1.6M int2 -> 29,577,216
    bf16*  H     = (bf16*) (ws + 16777216);             // overlay (6.4MB)
    bf16*  B     = (bf16*) (ws + 23177216);             // overlay (6.4MB)
    bf16*  A     = (bf16*) (ws + 29622272);             // 6.4MB -> 36,022,272

    if (ws_size < 40497152ull) {
        k_marker<<<(N_NODES + 255) / 256, 256, 0, stream>>>(out, N_NODES, 911.f);
        return;
    }

    k_count<<<NBLK, 256, 0, stream>>>(ei, x, w1, ghist, A, stats);
    k_tot<<<NCB, 256, 0, stream>>>(ghist, tot, x, xsum);
    k_rowscan<<<NCB, 256, 0, stream>>>(ghist, tot, cbase);
    k_cscatter<<<NBLK, 256, 0, stream>>>(ei, ew, ghist, cse);
    k_fine<<<NCB, 256, 0, stream>>>(cse, cbase, epk, off, dinv);
    k_norm<<<6250, 256, 0, stream>>>(epk, dinv);
    k_gcn<<<1563, 256, 0, stream>>>(off, epk, A, dinv, b1, B, bn1sum, bn1sq);
    k_aff_xw<<<12500, 256, 0, stream>>>(B, bn1sum, bn1sq, g1, be1, w2, H, A);
    k_gcn<<<1563, 256, 0, stream>>>(off, epk, A, dinv, b2, B, bn2sum, bn2sq);
    k_final<<<782, 256, 0, stream>>>(H, B, bn2sum, bn2sq, g2, be2, xsum,
                                     wih1, wih2, fw1, fw2, fb2, fb1,
                                     bih1, bhh1, bih2, bhh2, out);
}